// Round 9
// baseline (1586.001 us; speedup 1.0000x reference)
//
#include <hip/hip_runtime.h>
#include <hip/hip_bf16.h>
#include <math.h>

// RQ-VAE pipeline. Index path = numpy-fp32 bit-exact (validated r3-r6).
// Round 9: vq6 — LDS-free VQ. 4 waves/block over 64 rows; wave w scans col
// quarter [w*128,(w+1)*128) with wave-uniform codebook reads (L1/L2 broadcast,
// no staging); lexicographic 4-way merge in 2KB LDS (== np first-min, r4-
// validated rule). Occupancy now grid/VGPR-bound (8 blocks/CU) instead of
// LDS-bound (2). All fp chains identical to r6. GEMMs/decoder = r6-exact.

#define N_ROWS 131072
#define D_IN   384
#define H_DIM  256
#define L_DIM  32
#define K_CB   512
#define Q_ST   4
#define VQ_RPB 64                  // rows per VQ block
#define NPART  (N_ROWS / VQ_RPB)   // 2048 commit partials

typedef __attribute__((ext_vector_type(8))) short short8v;
typedef __attribute__((ext_vector_type(4))) float f32x4;

__device__ __forceinline__ ushort f2bf(float v)
{
    __hip_bfloat16 b = __float2bfloat16(v);
    return *reinterpret_cast<ushort*>(&b);
}

// np.sum(v*v) for n=32: numpy pairwise 8-accumulator order, products pre-rounded.
__device__ __forceinline__ float np_sumsq32(const float* __restrict__ v)
{
    #pragma clang fp contract(off)
    float s0 = v[0]*v[0], s1 = v[1]*v[1], s2 = v[2]*v[2], s3 = v[3]*v[3];
    float s4 = v[4]*v[4], s5 = v[5]*v[5], s6 = v[6]*v[6], s7 = v[7]*v[7];
    s0 = s0 + v[8]*v[8];   s1 = s1 + v[9]*v[9];   s2 = s2 + v[10]*v[10]; s3 = s3 + v[11]*v[11];
    s4 = s4 + v[12]*v[12]; s5 = s5 + v[13]*v[13]; s6 = s6 + v[14]*v[14]; s7 = s7 + v[15]*v[15];
    s0 = s0 + v[16]*v[16]; s1 = s1 + v[17]*v[17]; s2 = s2 + v[18]*v[18]; s3 = s3 + v[19]*v[19];
    s4 = s4 + v[20]*v[20]; s5 = s5 + v[21]*v[21]; s6 = s6 + v[22]*v[22]; s7 = s7 + v[23]*v[23];
    s0 = s0 + v[24]*v[24]; s1 = s1 + v[25]*v[25]; s2 = s2 + v[26]*v[26]; s3 = s3 + v[27]*v[27];
    s4 = s4 + v[28]*v[28]; s5 = s5 + v[29]*v[29]; s6 = s6 + v[30]*v[30]; s7 = s7 + v[31]*v[31];
    return ((s0 + s1) + (s2 + s3)) + ((s4 + s5) + (s6 + s7));
}

// ---------------- fp32 tiled GEMM (encoder; bit-exact path; r6 version) -----------
template<bool RELU>
__global__ __launch_bounds__(256)
void gemm_bias(const float* __restrict__ A, const float* __restrict__ B,
               const float* __restrict__ bias, float* __restrict__ C,
               int K, int Nout)
{
    #pragma clang fp contract(off)
    __shared__ float As2[32][132];   // [k][row]
    __shared__ float Bs[32][128];    // [k][col]
    const int t  = threadIdx.x;
    const int tc = t & 15;
    const int tr = t >> 4;
    const size_t row0 = (size_t)blockIdx.x * 128;
    const int    col0 = blockIdx.y * 128;

    float acc[8][8];
    #pragma unroll
    for (int i = 0; i < 8; ++i)
        #pragma unroll
        for (int j = 0; j < 8; ++j) acc[i][j] = 0.f;

    const int ar = t >> 3, ak = (t & 7) << 2;
    const int br = t >> 5, bc = (t & 31) << 2;

    for (int k0 = 0; k0 < K; k0 += 32) {
        #pragma unroll
        for (int i = 0; i < 4; ++i) {
            int r = ar + (i << 5);
            float4 v = *reinterpret_cast<const float4*>(A + (row0 + r) * (size_t)K + k0 + ak);
            As2[ak + 0][r] = v.x; As2[ak + 1][r] = v.y;
            As2[ak + 2][r] = v.z; As2[ak + 3][r] = v.w;
        }
        #pragma unroll
        for (int i = 0; i < 4; ++i) {
            int r = br + (i << 3);
            float4 v = *reinterpret_cast<const float4*>(B + (size_t)(k0 + r) * Nout + col0 + bc);
            *reinterpret_cast<float4*>(&Bs[r][bc]) = v;
        }
        __syncthreads();
        #pragma unroll
        for (int k = 0; k < 32; ++k) {
            float a[8], b[8];
            *reinterpret_cast<float4*>(&a[0]) = *reinterpret_cast<const float4*>(&As2[k][tr << 3]);
            *reinterpret_cast<float4*>(&a[4]) = *reinterpret_cast<const float4*>(&As2[k][(tr << 3) + 4]);
            *reinterpret_cast<float4*>(&b[0]) = *reinterpret_cast<const float4*>(&Bs[k][tc << 2]);
            *reinterpret_cast<float4*>(&b[4]) = *reinterpret_cast<const float4*>(&Bs[k][(tc << 2) + 64]);
            #pragma unroll
            for (int i = 0; i < 8; ++i)
                #pragma unroll
                for (int j = 0; j < 8; ++j) acc[i][j] = fmaf(a[i], b[j], acc[i][j]);
        }
        __syncthreads();
    }

    #pragma unroll
    for (int i = 0; i < 8; ++i) {
        size_t r = row0 + (tr << 3) + i;
        int c1 = col0 + (tc << 2);
        int c2 = c1 + 64;
        float v1[4], v2[4];
        #pragma unroll
        for (int j = 0; j < 4; ++j) {
            float u1 = acc[i][j]     + bias[c1 + j];
            float u2 = acc[i][j + 4] + bias[c2 + j];
            if (RELU) { u1 = fmaxf(u1, 0.0f); u2 = fmaxf(u2, 0.0f); }
            v1[j] = u1; v2[j] = u2;
        }
        *reinterpret_cast<float4*>(C + r * Nout + c1) = *reinterpret_cast<float4*>(&v1[0]);
        *reinterpret_cast<float4*>(C + r * Nout + c2) = *reinterpret_cast<float4*>(&v2[0]);
    }
}

// ---------------- z-GEMM: Z[M,32] = A[M,256] @ W[256,32] + b (bit-exact) ----------
__global__ __launch_bounds__(256)
void gemm_z(const float* __restrict__ A, const float* __restrict__ W,
            const float* __restrict__ bv, float* __restrict__ Z)
{
    #pragma clang fp contract(off)
    __shared__ float As2[32][132];
    __shared__ float Ws[32][36];
    const int t = threadIdx.x;
    const int cgz = t & 7, rgz = t >> 3;
    const size_t row0 = (size_t)blockIdx.x * 128;

    float acc[4][4];
    #pragma unroll
    for (int i = 0; i < 4; ++i)
        #pragma unroll
        for (int j = 0; j < 4; ++j) acc[i][j] = 0.f;

    const int ar = t >> 3, ak = (t & 7) << 2;
    for (int k0 = 0; k0 < H_DIM; k0 += 32) {
        #pragma unroll
        for (int i = 0; i < 4; ++i) {
            int r = ar + (i << 5);
            float4 v = *reinterpret_cast<const float4*>(A + (row0 + r) * (size_t)H_DIM + k0 + ak);
            As2[ak + 0][r] = v.x; As2[ak + 1][r] = v.y;
            As2[ak + 2][r] = v.z; As2[ak + 3][r] = v.w;
        }
        {
            int kr = t >> 3, cc = (t & 7) << 2;
            float4 v = *reinterpret_cast<const float4*>(W + (size_t)(k0 + kr) * L_DIM + cc);
            *reinterpret_cast<float4*>(&Ws[kr][cc]) = v;
        }
        __syncthreads();
        #pragma unroll
        for (int k = 0; k < 32; ++k) {
            float a[4], w[4];
            *reinterpret_cast<float4*>(&a[0]) = *reinterpret_cast<const float4*>(&As2[k][rgz << 2]);
            *reinterpret_cast<float4*>(&w[0]) = *reinterpret_cast<const float4*>(&Ws[k][cgz << 2]);
            #pragma unroll
            for (int i = 0; i < 4; ++i)
                #pragma unroll
                for (int j = 0; j < 4; ++j) acc[i][j] = fmaf(a[i], w[j], acc[i][j]);
        }
        __syncthreads();
    }
    #pragma unroll
    for (int i = 0; i < 4; ++i) {
        size_t row = row0 + (rgz << 2) + i;
        float v[4];
        #pragma unroll
        for (int j = 0; j < 4; ++j) v[j] = acc[i][j] + bv[(cgz << 2) + j];
        *reinterpret_cast<float4*>(Z + row * L_DIM + (cgz << 2)) = *reinterpret_cast<float4*>(&v[0]);
    }
}

// ---------------- cnorm (numpy order) ---------------------------------------------
__global__ __launch_bounds__(256)
void cnorm_kernel(const float* __restrict__ cbs, float* __restrict__ cnorm)
{
    #pragma clang fp contract(off)
    int g = blockIdx.x * 256 + threadIdx.x;
    const float* c = cbs + (size_t)g * L_DIM;
    float cl[L_DIM];
    #pragma unroll
    for (int l = 0; l < L_DIM; ++l) cl[l] = c[l];
    cnorm[g] = np_sumsq32(cl);
}

// ---------------- dec-weight prep: fp32 [K][N] -> bf16 transposed [N][K] ----------
__global__ __launch_bounds__(256)
void prep_wt(const float* __restrict__ W, ushort* __restrict__ Wt, int K, int N)
{
    int g = blockIdx.x * 256 + threadIdx.x;
    if (g >= K * N) return;
    int n = g / K, k = g - n * K;
    Wt[g] = f2bf(W[(size_t)k * N + n]);
}

// ---------------- residual VQ v6: LDS-free, 4-wave col-split ----------------------
// Block: 256 thr = 4 waves, 64 rows (1 row per lane, same 64 rows in every
// wave). Wave w scans cols [w*128,(w+1)*128): all codebook/cnorm reads are
// wave-uniform -> scalar/broadcast loads from L1/L2, NO LDS staging. Per-wave
// (bd,bi) merged lexicographically (strict < on d, ascending wave order ==
// np.argmin first-min, validated r4). All fp chains identical to r6 vq3.
__global__ __launch_bounds__(256)
void vq6_kernel(const float* __restrict__ zbuf, const float* __restrict__ cbs,
                const float* __restrict__ cnorm_g, ushort* __restrict__ zqb,
                float* __restrict__ idxOut, double* __restrict__ commitPart,
                int rowBase)
{
    #pragma clang fp contract(off)
    __shared__ float  sd[4][64];
    __shared__ int    si[4][64];
    __shared__ double sred[256];

    const int t = threadIdx.x;
    const int w = t >> 6;        // wave id = col quarter
    const int l = t & 63;        // lane = row within block
    const size_t lrow = (size_t)blockIdx.x * VQ_RPB + l;
    const size_t grow = (size_t)rowBase + lrow;
    const int c0 = w << 7;       // this wave's col base

    // every wave holds row l's residual (kept identical across waves)
    float r[L_DIM];
    {
        const float4* zp = reinterpret_cast<const float4*>(zbuf + lrow * L_DIM);
        #pragma unroll
        for (int j = 0; j < 8; ++j) {
            float4 v = zp[j];
            r[4*j+0]=v.x; r[4*j+1]=v.y; r[4*j+2]=v.z; r[4*j+3]=v.w;
        }
    }

    int bidx[Q_ST];
    double cAcc = 0.0;

    #pragma unroll 1
    for (int q = 0; q < Q_ST; ++q) {
        const float* cbq = cbs + (size_t)q * K_CB * L_DIM;
        const float* cnq = cnorm_g + q * K_CB;

        float rr = np_sumsq32(r);
        float bd = __builtin_inff();
        int   bi = c0;

        #pragma unroll 2
        for (int cc = 0; cc < 128; cc += 2) {
            const int c = c0 + cc;
            const float4* w0 = reinterpret_cast<const float4*>(cbq + ((size_t)c << 5));
            const float4* w1 = w0 + 8;
            float a0 = 0.f, a1 = 0.f;   // single sequential FMA chain per col
            #pragma unroll
            for (int j = 0; j < 8; ++j) {
                float4 u = w0[j], v = w1[j];   // wave-uniform -> broadcast load
                a0 = fmaf(r[4*j+0], u.x, a0);  a1 = fmaf(r[4*j+0], v.x, a1);
                a0 = fmaf(r[4*j+1], u.y, a0);  a1 = fmaf(r[4*j+1], v.y, a1);
                a0 = fmaf(r[4*j+2], u.z, a0);  a1 = fmaf(r[4*j+2], v.z, a1);
                a0 = fmaf(r[4*j+3], u.w, a0);  a1 = fmaf(r[4*j+3], v.w, a1);
            }
            float d0 = (rr - 2.0f * a0) + cnq[c];
            float d1 = (rr - 2.0f * a1) + cnq[c + 1];
            if (d0 < bd) { bd = d0; bi = c; }       // strict < = first-min in range
            if (d1 < bd) { bd = d1; bi = c + 1; }
        }

        __syncthreads();   // prior stage's sd/si reads complete
        sd[w][l] = bd;
        si[w][l] = bi;
        __syncthreads();

        // 4-way lexicographic merge (every wave computes its lane's winner)
        float gb = sd[0][l]; int gi = si[0][l];
        #pragma unroll
        for (int ww = 1; ww < 4; ++ww) {
            float od = sd[ww][l]; int oi = si[ww][l];
            if (od < gb) { gb = od; gi = oi; }   // tie keeps lower wave = lower col
        }
        bidx[q] = gi;

        // residual + commit update from global codeword (L1/L2-hot gather),
        // identical op order in every wave -> r stays identical across waves
        {
            const float4* pw = reinterpret_cast<const float4*>(cbq + ((size_t)gi << 5));
            float cs = 0.f;
            #pragma unroll
            for (int j = 0; j < 8; ++j) {
                float4 v = pw[j];
                float df;
                df = v.x - r[4*j+0]; cs = fmaf(df, df, cs); r[4*j+0] = r[4*j+0] - v.x;
                df = v.y - r[4*j+1]; cs = fmaf(df, df, cs); r[4*j+1] = r[4*j+1] - v.y;
                df = v.z - r[4*j+2]; cs = fmaf(df, df, cs); r[4*j+2] = r[4*j+2] - v.z;
                df = v.w - r[4*j+3]; cs = fmaf(df, df, cs); r[4*j+3] = r[4*j+3] - v.w;
            }
            cAcc += (double)cs;
        }
    }

    if (w == 0) {
        // indices: one float4 per row
        float4 iv = make_float4((float)bidx[0], (float)bidx[1], (float)bidx[2], (float)bidx[3]);
        *reinterpret_cast<float4*>(idxOut + grow * Q_ST) = iv;

        // z_q = z - r_final (re-read z), stored bf16 for the MFMA decoder
        const float4* zp = reinterpret_cast<const float4*>(zbuf + lrow * L_DIM);
        ushort zq16[L_DIM];
        #pragma unroll
        for (int j = 0; j < 8; ++j) {
            float4 v = zp[j];
            zq16[4*j+0] = f2bf(v.x - r[4*j+0]);
            zq16[4*j+1] = f2bf(v.y - r[4*j+1]);
            zq16[4*j+2] = f2bf(v.z - r[4*j+2]);
            zq16[4*j+3] = f2bf(v.w - r[4*j+3]);
        }
        uint4* o = reinterpret_cast<uint4*>(zqb + lrow * L_DIM);
        const uint4* s = reinterpret_cast<const uint4*>(zq16);
        #pragma unroll
        for (int j = 0; j < 4; ++j) o[j] = s[j];
    }

    // deterministic commit reduction (wave 0 contributes; others add 0)
    sred[t] = (w == 0) ? cAcc : 0.0;
    __syncthreads();
    for (int s = 128; s > 0; s >>= 1) {
        if (t < s) sred[t] += sred[t + s];
        __syncthreads();
    }
    if (t == 0) commitPart[rowBase / VQ_RPB + blockIdx.x] = sred[0];
}

// ---------------- bf16 MFMA GEMM (decoder; r6 version) ----------------------------
template<bool RELU, bool OUTBF16>
__global__ __launch_bounds__(256)
void mfma_gemm(const ushort* __restrict__ A, const ushort* __restrict__ Bt,
               const float* __restrict__ bias, void* __restrict__ Cout,
               int K, int Nout)
{
    __shared__ ushort As[128][40];
    __shared__ ushort Bs[128][40];
    const int t    = threadIdx.x;
    const int lane = t & 63;
    const int wid  = t >> 6;
    const int wr = wid >> 1, wc = wid & 1;
    const size_t row0 = (size_t)blockIdx.x * 128;
    const int    col0 = blockIdx.y * 128;

    f32x4 acc[4][4] = {};
    const int srow = t >> 1;
    const int sh   = (t & 1) << 4;

    for (int k0 = 0; k0 < K; k0 += 32) {
        {
            const ushort* ap = A + (row0 + srow) * (size_t)K + k0 + sh;
            uint4 v0 = *reinterpret_cast<const uint4*>(ap);
            uint4 v1 = *reinterpret_cast<const uint4*>(ap + 8);
            *reinterpret_cast<uint4*>(&As[srow][sh])     = v0;
            *reinterpret_cast<uint4*>(&As[srow][sh + 8]) = v1;
            const ushort* bp = Bt + (size_t)(col0 + srow) * K + k0 + sh;
            uint4 w0 = *reinterpret_cast<const uint4*>(bp);
            uint4 w1 = *reinterpret_cast<const uint4*>(bp + 8);
            *reinterpret_cast<uint4*>(&Bs[srow][sh])     = w0;
            *reinterpret_cast<uint4*>(&Bs[srow][sh + 8]) = w1;
        }
        __syncthreads();
        const int l15 = lane & 15, lk = (lane >> 4) << 3;
        short8v af[4], bf[4];
        #pragma unroll
        for (int f = 0; f < 4; ++f) {
            af[f] = *reinterpret_cast<const short8v*>(&As[(wr << 6) + (f << 4) + l15][lk]);
            bf[f] = *reinterpret_cast<const short8v*>(&Bs[(wc << 6) + (f << 4) + l15][lk]);
        }
        #pragma unroll
        for (int i = 0; i < 4; ++i)
            #pragma unroll
            for (int j = 0; j < 4; ++j)
                acc[i][j] = __builtin_amdgcn_mfma_f32_16x16x32_bf16(af[i], bf[j], acc[i][j], 0, 0, 0);
        __syncthreads();
    }

    const int l15 = lane & 15, lr4 = (lane >> 4) << 2;
    #pragma unroll
    for (int i = 0; i < 4; ++i) {
        #pragma unroll
        for (int j = 0; j < 4; ++j) {
            int col = col0 + (wc << 6) + (j << 4) + l15;
            float bv = bias[col];
            #pragma unroll
            for (int rj = 0; rj < 4; ++rj) {
                size_t row = row0 + (wr << 6) + (i << 4) + lr4 + rj;
                float v = acc[i][j][rj] + bv;
                if (RELU) v = fmaxf(v, 0.f);
                if (OUTBF16)
                    reinterpret_cast<ushort*>(Cout)[row * Nout + col] = f2bf(v);
                else
                    reinterpret_cast<float*>(Cout)[row * Nout + col] = v;
            }
        }
    }
}

// ---------------- final commit reduction (2048 partials) --------------------------
__global__ __launch_bounds__(256)
void commit_finalize(const double* __restrict__ commitPart, float* __restrict__ outCommit)
{
    __shared__ double sred[256];
    const int t = threadIdx.x;
    double s = 0.0;
    for (int i = t; i < NPART; i += 256) s += commitPart[i];
    sred[t] = s;
    __syncthreads();
    for (int st = 128; st > 0; st >>= 1) {
        if (t < st) sred[t] += sred[t + st];
        __syncthreads();
    }
    if (t == 0)
        outCommit[0] = (float)(sred[0] / ((double)N_ROWS * (double)L_DIM));
}

extern "C" void kernel_launch(void* const* d_in, const int* in_sizes, int n_in,
                              void* d_out, int out_size, void* d_ws, size_t ws_size,
                              hipStream_t stream)
{
    const float* x      = (const float*)d_in[0];
    const float* enc_w1 = (const float*)d_in[1];
    const float* enc_b1 = (const float*)d_in[2];
    const float* enc_w2 = (const float*)d_in[3];
    const float* enc_b2 = (const float*)d_in[4];
    const float* enc_w3 = (const float*)d_in[5];
    const float* enc_b3 = (const float*)d_in[6];
    const float* dec_w1 = (const float*)d_in[7];
    const float* dec_b1 = (const float*)d_in[8];
    const float* dec_w2 = (const float*)d_in[9];
    const float* dec_b2 = (const float*)d_in[10];
    const float* dec_w3 = (const float*)d_in[11];
    const float* dec_b3 = (const float*)d_in[12];
    const float* cbs    = (const float*)d_in[13];

    float* out       = (float*)d_out;
    float* xrec      = out;
    float* idxOut    = out + (size_t)N_ROWS * D_IN;
    float* commitOut = idxOut + (size_t)N_ROWS * Q_ST;

    // ws layout:
    //   cnorm  f32[2048]     @0      (8192)
    //   commit f64[2048]     @8192   (16384)
    //   w1t    u16[256*32]   @24576  (16384)
    //   w2t    u16[256*256]  @40960  (131072)
    //   w3t    u16[384*256]  @172032 (196608)
    //   bufs                 @368640
    char*   wsb        = (char*)d_ws;
    float*  cnorm      = (float*)wsb;
    double* commitPart = (double*)(wsb + 8192);
    ushort* w1t        = (ushort*)(wsb + 24576);
    ushort* w2t        = (ushort*)(wsb + 40960);
    ushort* w3t        = (ushort*)(wsb + 172032);
    char*   bufs       = wsb + 368640;

    // per-row bytes: zbuf 128 + bufA 1024 + bufB 1024 + zqb 64 + h1b 512 + h2b 512 = 3264
    size_t availB = (ws_size > 368640) ? ws_size - 368640 : 0;
    long long chunk = (long long)(availB / 3264);
    chunk = (chunk / 256) * 256;
    if (chunk > N_ROWS) chunk = N_ROWS;
    if (chunk < 256) chunk = 256;

    float*  zbuf = (float*)bufs;
    float*  bufA = zbuf + (size_t)chunk * L_DIM;
    float*  bufB = bufA + (size_t)chunk * H_DIM;
    ushort* zqb  = (ushort*)(bufB + (size_t)chunk * H_DIM);
    ushort* h1b  = zqb + (size_t)chunk * L_DIM;
    ushort* h2b  = h1b + (size_t)chunk * H_DIM;

    cnorm_kernel<<<8, 256, 0, stream>>>(cbs, cnorm);
    prep_wt<<<(L_DIM  * H_DIM + 255) / 256, 256, 0, stream>>>(dec_w1, w1t, L_DIM, H_DIM);
    prep_wt<<<(H_DIM * H_DIM + 255) / 256, 256, 0, stream>>>(dec_w2, w2t, H_DIM, H_DIM);
    prep_wt<<<(H_DIM * D_IN + 255) / 256, 256, 0, stream>>>(dec_w3, w3t, H_DIM, D_IN);

    for (long long ro = 0; ro < N_ROWS; ro += chunk) {
        long long R = N_ROWS - ro;
        if (R > chunk) R = chunk;
        dim3 g2((unsigned)(R / 128), 2);
        dim3 g3((unsigned)(R / 128), 3);
        // encoder (bit-exact fp32)
        gemm_bias<true><<<g2, 256, 0, stream>>>(x + ro * D_IN, enc_w1, enc_b1, bufA, D_IN, H_DIM);
        gemm_bias<true><<<g2, 256, 0, stream>>>(bufA, enc_w2, enc_b2, bufB, H_DIM, H_DIM);
        gemm_z<<<(unsigned)(R / 128), 256, 0, stream>>>(bufB, enc_w3, enc_b3, zbuf);
        // residual VQ (bit-exact; writes bf16 z_q)
        vq6_kernel<<<(unsigned)(R / VQ_RPB), 256, 0, stream>>>(zbuf, cbs, cnorm, zqb,
                                                               idxOut, commitPart, (int)ro);
        // decoder (bf16 MFMA)
        mfma_gemm<true,  true ><<<g2, 256, 0, stream>>>(zqb, w1t, dec_b1, h1b, L_DIM, H_DIM);
        mfma_gemm<true,  true ><<<g2, 256, 0, stream>>>(h1b, w2t, dec_b2, h2b, H_DIM, H_DIM);
        mfma_gemm<false, false><<<g3, 256, 0, stream>>>(h2b, w3t, dec_b3, xrec + ro * D_IN, H_DIM, D_IN);
    }

    commit_finalize<<<1, 256, 0, stream>>>(commitPart, commitOut);
}

// Round 10
// 1067.912 us; speedup vs baseline: 1.4851x; 1.4851x over previous
//
#include <hip/hip_runtime.h>
#include <hip/hip_bf16.h>
#include <math.h>

// RQ-VAE pipeline. Index path = numpy-fp32 bit-exact (validated r3-r6).
// Round 10: revert to r6 config; vq7 = vq3 with 2 rows/lane so both rows share
// each broadcast codebook ds_read (halves LDS-pipe instructions per unit work,
// the measured binding constraint: 18 DS-instr/pair-iter ~= 850K cyc/CU = r6's
// 345us). 128 thr x 256 rows/block -> 512 blocks, 2/CU. Per-row fp chains
// unchanged.

#define N_ROWS 131072
#define D_IN   384
#define H_DIM  256
#define L_DIM  32
#define K_CB   512
#define Q_ST   4
#define VQ_RPB 256                 // rows per VQ block
#define NPART  (N_ROWS / VQ_RPB)   // 512 commit partials

typedef __attribute__((ext_vector_type(8))) short short8v;
typedef __attribute__((ext_vector_type(4))) float f32x4;

__device__ __forceinline__ ushort f2bf(float v)
{
    __hip_bfloat16 b = __float2bfloat16(v);
    return *reinterpret_cast<ushort*>(&b);
}

// np.sum(v*v) for n=32: numpy pairwise 8-accumulator order, products pre-rounded.
__device__ __forceinline__ float np_sumsq32(const float* __restrict__ v)
{
    #pragma clang fp contract(off)
    float s0 = v[0]*v[0], s1 = v[1]*v[1], s2 = v[2]*v[2], s3 = v[3]*v[3];
    float s4 = v[4]*v[4], s5 = v[5]*v[5], s6 = v[6]*v[6], s7 = v[7]*v[7];
    s0 = s0 + v[8]*v[8];   s1 = s1 + v[9]*v[9];   s2 = s2 + v[10]*v[10]; s3 = s3 + v[11]*v[11];
    s4 = s4 + v[12]*v[12]; s5 = s5 + v[13]*v[13]; s6 = s6 + v[14]*v[14]; s7 = s7 + v[15]*v[15];
    s0 = s0 + v[16]*v[16]; s1 = s1 + v[17]*v[17]; s2 = s2 + v[18]*v[18]; s3 = s3 + v[19]*v[19];
    s4 = s4 + v[20]*v[20]; s5 = s5 + v[21]*v[21]; s6 = s6 + v[22]*v[22]; s7 = s7 + v[23]*v[23];
    s0 = s0 + v[24]*v[24]; s1 = s1 + v[25]*v[25]; s2 = s2 + v[26]*v[26]; s3 = s3 + v[27]*v[27];
    s4 = s4 + v[28]*v[28]; s5 = s5 + v[29]*v[29]; s6 = s6 + v[30]*v[30]; s7 = s7 + v[31]*v[31];
    return ((s0 + s1) + (s2 + s3)) + ((s4 + s5) + (s6 + s7));
}

// ---------------- fp32 tiled GEMM (encoder; bit-exact path; r6 version) -----------
template<bool RELU>
__global__ __launch_bounds__(256)
void gemm_bias(const float* __restrict__ A, const float* __restrict__ B,
               const float* __restrict__ bias, float* __restrict__ C,
               int K, int Nout)
{
    #pragma clang fp contract(off)
    __shared__ float As2[32][132];   // [k][row]
    __shared__ float Bs[32][128];    // [k][col]
    const int t  = threadIdx.x;
    const int tc = t & 15;
    const int tr = t >> 4;
    const size_t row0 = (size_t)blockIdx.x * 128;
    const int    col0 = blockIdx.y * 128;

    float acc[8][8];
    #pragma unroll
    for (int i = 0; i < 8; ++i)
        #pragma unroll
        for (int j = 0; j < 8; ++j) acc[i][j] = 0.f;

    const int ar = t >> 3, ak = (t & 7) << 2;
    const int br = t >> 5, bc = (t & 31) << 2;

    for (int k0 = 0; k0 < K; k0 += 32) {
        #pragma unroll
        for (int i = 0; i < 4; ++i) {
            int r = ar + (i << 5);
            float4 v = *reinterpret_cast<const float4*>(A + (row0 + r) * (size_t)K + k0 + ak);
            As2[ak + 0][r] = v.x; As2[ak + 1][r] = v.y;
            As2[ak + 2][r] = v.z; As2[ak + 3][r] = v.w;
        }
        #pragma unroll
        for (int i = 0; i < 4; ++i) {
            int r = br + (i << 3);
            float4 v = *reinterpret_cast<const float4*>(B + (size_t)(k0 + r) * Nout + col0 + bc);
            *reinterpret_cast<float4*>(&Bs[r][bc]) = v;
        }
        __syncthreads();
        #pragma unroll
        for (int k = 0; k < 32; ++k) {
            float a[8], b[8];
            *reinterpret_cast<float4*>(&a[0]) = *reinterpret_cast<const float4*>(&As2[k][tr << 3]);
            *reinterpret_cast<float4*>(&a[4]) = *reinterpret_cast<const float4*>(&As2[k][(tr << 3) + 4]);
            *reinterpret_cast<float4*>(&b[0]) = *reinterpret_cast<const float4*>(&Bs[k][tc << 2]);
            *reinterpret_cast<float4*>(&b[4]) = *reinterpret_cast<const float4*>(&Bs[k][(tc << 2) + 64]);
            #pragma unroll
            for (int i = 0; i < 8; ++i)
                #pragma unroll
                for (int j = 0; j < 8; ++j) acc[i][j] = fmaf(a[i], b[j], acc[i][j]);
        }
        __syncthreads();
    }

    #pragma unroll
    for (int i = 0; i < 8; ++i) {
        size_t r = row0 + (tr << 3) + i;
        int c1 = col0 + (tc << 2);
        int c2 = c1 + 64;
        float v1[4], v2[4];
        #pragma unroll
        for (int j = 0; j < 4; ++j) {
            float u1 = acc[i][j]     + bias[c1 + j];
            float u2 = acc[i][j + 4] + bias[c2 + j];
            if (RELU) { u1 = fmaxf(u1, 0.0f); u2 = fmaxf(u2, 0.0f); }
            v1[j] = u1; v2[j] = u2;
        }
        *reinterpret_cast<float4*>(C + r * Nout + c1) = *reinterpret_cast<float4*>(&v1[0]);
        *reinterpret_cast<float4*>(C + r * Nout + c2) = *reinterpret_cast<float4*>(&v2[0]);
    }
}

// ---------------- z-GEMM: Z[M,32] = A[M,256] @ W[256,32] + b (bit-exact) ----------
__global__ __launch_bounds__(256)
void gemm_z(const float* __restrict__ A, const float* __restrict__ W,
            const float* __restrict__ bv, float* __restrict__ Z)
{
    #pragma clang fp contract(off)
    __shared__ float As2[32][132];
    __shared__ float Ws[32][36];
    const int t = threadIdx.x;
    const int cgz = t & 7, rgz = t >> 3;
    const size_t row0 = (size_t)blockIdx.x * 128;

    float acc[4][4];
    #pragma unroll
    for (int i = 0; i < 4; ++i)
        #pragma unroll
        for (int j = 0; j < 4; ++j) acc[i][j] = 0.f;

    const int ar = t >> 3, ak = (t & 7) << 2;
    for (int k0 = 0; k0 < H_DIM; k0 += 32) {
        #pragma unroll
        for (int i = 0; i < 4; ++i) {
            int r = ar + (i << 5);
            float4 v = *reinterpret_cast<const float4*>(A + (row0 + r) * (size_t)H_DIM + k0 + ak);
            As2[ak + 0][r] = v.x; As2[ak + 1][r] = v.y;
            As2[ak + 2][r] = v.z; As2[ak + 3][r] = v.w;
        }
        {
            int kr = t >> 3, cc = (t & 7) << 2;
            float4 v = *reinterpret_cast<const float4*>(W + (size_t)(k0 + kr) * L_DIM + cc);
            *reinterpret_cast<float4*>(&Ws[kr][cc]) = v;
        }
        __syncthreads();
        #pragma unroll
        for (int k = 0; k < 32; ++k) {
            float a[4], w[4];
            *reinterpret_cast<float4*>(&a[0]) = *reinterpret_cast<const float4*>(&As2[k][rgz << 2]);
            *reinterpret_cast<float4*>(&w[0]) = *reinterpret_cast<const float4*>(&Ws[k][cgz << 2]);
            #pragma unroll
            for (int i = 0; i < 4; ++i)
                #pragma unroll
                for (int j = 0; j < 4; ++j) acc[i][j] = fmaf(a[i], w[j], acc[i][j]);
        }
        __syncthreads();
    }
    #pragma unroll
    for (int i = 0; i < 4; ++i) {
        size_t row = row0 + (rgz << 2) + i;
        float v[4];
        #pragma unroll
        for (int j = 0; j < 4; ++j) v[j] = acc[i][j] + bv[(cgz << 2) + j];
        *reinterpret_cast<float4*>(Z + row * L_DIM + (cgz << 2)) = *reinterpret_cast<float4*>(&v[0]);
    }
}

// ---------------- cnorm (numpy order) ---------------------------------------------
__global__ __launch_bounds__(256)
void cnorm_kernel(const float* __restrict__ cbs, float* __restrict__ cnorm)
{
    #pragma clang fp contract(off)
    int g = blockIdx.x * 256 + threadIdx.x;
    const float* c = cbs + (size_t)g * L_DIM;
    float cl[L_DIM];
    #pragma unroll
    for (int l = 0; l < L_DIM; ++l) cl[l] = c[l];
    cnorm[g] = np_sumsq32(cl);
}

// ---------------- dec-weight prep: fp32 [K][N] -> bf16 transposed [N][K] ----------
__global__ __launch_bounds__(256)
void prep_wt(const float* __restrict__ W, ushort* __restrict__ Wt, int K, int N)
{
    int g = blockIdx.x * 256 + threadIdx.x;
    if (g >= K * N) return;
    int n = g / K, k = g - n * K;
    Wt[g] = f2bf(W[(size_t)k * N + n]);
}

// ---------------- residual VQ v7: broadcast scan, 2 rows/lane ---------------------
// 128 thr/block, 256 rows/block (lane t owns rows t and t+128). Full 64KB
// codebook staged per stage; each broadcast ds_read serves BOTH rows' FMA
// chains (halves LDS-pipe instrs per row-scan vs vq3). Per-row fp chains and
// strict-< ascending argmin identical to r6 vq3 (np first-min).
__global__ __launch_bounds__(128)
void vq7_kernel(const float* __restrict__ zbuf, const float* __restrict__ cbs,
                const float* __restrict__ cnorm_g, ushort* __restrict__ zqb,
                float* __restrict__ idxOut, double* __restrict__ commitPart,
                int rowBase)
{
    #pragma clang fp contract(off)
    __shared__ float  cbL[K_CB * L_DIM];   // 64 KB
    __shared__ float  cnL[K_CB];           // 2 KB
    __shared__ double sred[128];           // 1 KB

    const int t = threadIdx.x;
    const size_t lrow0 = (size_t)blockIdx.x * VQ_RPB + t;         // row A
    const size_t lrow1 = lrow0 + 128;                             // row B
    const size_t grow0 = (size_t)rowBase + lrow0;
    const size_t grow1 = (size_t)rowBase + lrow1;

    float r0[L_DIM], r1[L_DIM];
    {
        const float4* zp0 = reinterpret_cast<const float4*>(zbuf + lrow0 * L_DIM);
        const float4* zp1 = reinterpret_cast<const float4*>(zbuf + lrow1 * L_DIM);
        #pragma unroll
        for (int j = 0; j < 8; ++j) {
            float4 a = zp0[j], b = zp1[j];
            r0[4*j+0]=a.x; r0[4*j+1]=a.y; r0[4*j+2]=a.z; r0[4*j+3]=a.w;
            r1[4*j+0]=b.x; r1[4*j+1]=b.y; r1[4*j+2]=b.z; r1[4*j+3]=b.w;
        }
    }

    int bidx0[Q_ST], bidx1[Q_ST];
    double cAcc = 0.0;

    #pragma unroll 1
    for (int q = 0; q < Q_ST; ++q) {
        __syncthreads();   // prior stage's cbL reads done before overwrite
        {
            const float4* src = reinterpret_cast<const float4*>(cbs + (size_t)q * K_CB * L_DIM);
            float4* dst = reinterpret_cast<float4*>(cbL);
            #pragma unroll
            for (int i = 0; i < 32; ++i) dst[t + (i << 7)] = src[t + (i << 7)];
            #pragma unroll
            for (int i = 0; i < 4; ++i)
                cnL[t + (i << 7)] = cnorm_g[q * K_CB + t + (i << 7)];
        }
        __syncthreads();

        float rr0 = np_sumsq32(r0);
        float rr1 = np_sumsq32(r1);
        float bd0 = __builtin_inff(), bd1 = __builtin_inff();
        int   bi0 = 0, bi1 = 0;

        #pragma unroll 1
        for (int c = 0; c < K_CB; c += 2) {
            const float4* w0 = reinterpret_cast<const float4*>(cbL + (c << 5));
            const float4* w1 = w0 + 8;
            float a00 = 0.f, a01 = 0.f, a10 = 0.f, a11 = 0.f;
            #pragma unroll
            for (int j = 0; j < 8; ++j) {
                float4 u = w0[j], v = w1[j];   // broadcast reads shared by both rows
                a00 = fmaf(r0[4*j+0], u.x, a00);  a01 = fmaf(r0[4*j+0], v.x, a01);
                a10 = fmaf(r1[4*j+0], u.x, a10);  a11 = fmaf(r1[4*j+0], v.x, a11);
                a00 = fmaf(r0[4*j+1], u.y, a00);  a01 = fmaf(r0[4*j+1], v.y, a01);
                a10 = fmaf(r1[4*j+1], u.y, a10);  a11 = fmaf(r1[4*j+1], v.y, a11);
                a00 = fmaf(r0[4*j+2], u.z, a00);  a01 = fmaf(r0[4*j+2], v.z, a01);
                a10 = fmaf(r1[4*j+2], u.z, a10);  a11 = fmaf(r1[4*j+2], v.z, a11);
                a00 = fmaf(r0[4*j+3], u.w, a00);  a01 = fmaf(r0[4*j+3], v.w, a01);
                a10 = fmaf(r1[4*j+3], u.w, a10);  a11 = fmaf(r1[4*j+3], v.w, a11);
            }
            float cn0 = cnL[c], cn1 = cnL[c + 1];
            float d00 = (rr0 - 2.0f * a00) + cn0;
            float d01 = (rr0 - 2.0f * a01) + cn1;
            float d10 = (rr1 - 2.0f * a10) + cn0;
            float d11 = (rr1 - 2.0f * a11) + cn1;
            if (d00 < bd0) { bd0 = d00; bi0 = c; }       // strict < = np first-min
            if (d01 < bd0) { bd0 = d01; bi0 = c + 1; }
            if (d10 < bd1) { bd1 = d10; bi1 = c; }
            if (d11 < bd1) { bd1 = d11; bi1 = c + 1; }
        }
        bidx0[q] = bi0;
        bidx1[q] = bi1;

        // winner gathers from LDS (resident); residual + commit, np op order
        {
            const float4* p0 = reinterpret_cast<const float4*>(cbL + (bi0 << 5));
            const float4* p1 = reinterpret_cast<const float4*>(cbL + (bi1 << 5));
            float cs0 = 0.f, cs1 = 0.f;
            #pragma unroll
            for (int j = 0; j < 8; ++j) {
                float4 v0 = p0[j], v1 = p1[j];
                float df;
                df = v0.x - r0[4*j+0]; cs0 = fmaf(df, df, cs0); r0[4*j+0] = r0[4*j+0] - v0.x;
                df = v0.y - r0[4*j+1]; cs0 = fmaf(df, df, cs0); r0[4*j+1] = r0[4*j+1] - v0.y;
                df = v0.z - r0[4*j+2]; cs0 = fmaf(df, df, cs0); r0[4*j+2] = r0[4*j+2] - v0.z;
                df = v0.w - r0[4*j+3]; cs0 = fmaf(df, df, cs0); r0[4*j+3] = r0[4*j+3] - v0.w;
                df = v1.x - r1[4*j+0]; cs1 = fmaf(df, df, cs1); r1[4*j+0] = r1[4*j+0] - v1.x;
                df = v1.y - r1[4*j+1]; cs1 = fmaf(df, df, cs1); r1[4*j+1] = r1[4*j+1] - v1.y;
                df = v1.z - r1[4*j+2]; cs1 = fmaf(df, df, cs1); r1[4*j+2] = r1[4*j+2] - v1.z;
                df = v1.w - r1[4*j+3]; cs1 = fmaf(df, df, cs1); r1[4*j+3] = r1[4*j+3] - v1.w;
            }
            cAcc += (double)cs0;
            cAcc += (double)cs1;
        }
    }

    // indices: one float4 per row
    {
        float4 iv0 = make_float4((float)bidx0[0], (float)bidx0[1], (float)bidx0[2], (float)bidx0[3]);
        float4 iv1 = make_float4((float)bidx1[0], (float)bidx1[1], (float)bidx1[2], (float)bidx1[3]);
        *reinterpret_cast<float4*>(idxOut + grow0 * Q_ST) = iv0;
        *reinterpret_cast<float4*>(idxOut + grow1 * Q_ST) = iv1;
    }

    // z_q = z - r_final (re-read z), stored bf16 for the MFMA decoder
    {
        const float4* zp0 = reinterpret_cast<const float4*>(zbuf + lrow0 * L_DIM);
        const float4* zp1 = reinterpret_cast<const float4*>(zbuf + lrow1 * L_DIM);
        ushort zq0[L_DIM], zq1[L_DIM];
        #pragma unroll
        for (int j = 0; j < 8; ++j) {
            float4 a = zp0[j], b = zp1[j];
            zq0[4*j+0] = f2bf(a.x - r0[4*j+0]);
            zq0[4*j+1] = f2bf(a.y - r0[4*j+1]);
            zq0[4*j+2] = f2bf(a.z - r0[4*j+2]);
            zq0[4*j+3] = f2bf(a.w - r0[4*j+3]);
            zq1[4*j+0] = f2bf(b.x - r1[4*j+0]);
            zq1[4*j+1] = f2bf(b.y - r1[4*j+1]);
            zq1[4*j+2] = f2bf(b.z - r1[4*j+2]);
            zq1[4*j+3] = f2bf(b.w - r1[4*j+3]);
        }
        uint4* o0 = reinterpret_cast<uint4*>(zqb + lrow0 * L_DIM);
        uint4* o1 = reinterpret_cast<uint4*>(zqb + lrow1 * L_DIM);
        const uint4* s0 = reinterpret_cast<const uint4*>(zq0);
        const uint4* s1 = reinterpret_cast<const uint4*>(zq1);
        #pragma unroll
        for (int j = 0; j < 4; ++j) { o0[j] = s0[j]; o1[j] = s1[j]; }
    }

    sred[t] = cAcc;
    __syncthreads();
    for (int s = 64; s > 0; s >>= 1) {
        if (t < s) sred[t] += sred[t + s];
        __syncthreads();
    }
    if (t == 0) commitPart[rowBase / VQ_RPB + blockIdx.x] = sred[0];
}

// ---------------- bf16 MFMA GEMM (decoder; r6 version) ----------------------------
template<bool RELU, bool OUTBF16>
__global__ __launch_bounds__(256)
void mfma_gemm(const ushort* __restrict__ A, const ushort* __restrict__ Bt,
               const float* __restrict__ bias, void* __restrict__ Cout,
               int K, int Nout)
{
    __shared__ ushort As[128][40];
    __shared__ ushort Bs[128][40];
    const int t    = threadIdx.x;
    const int lane = t & 63;
    const int wid  = t >> 6;
    const int wr = wid >> 1, wc = wid & 1;
    const size_t row0 = (size_t)blockIdx.x * 128;
    const int    col0 = blockIdx.y * 128;

    f32x4 acc[4][4] = {};
    const int srow = t >> 1;
    const int sh   = (t & 1) << 4;

    for (int k0 = 0; k0 < K; k0 += 32) {
        {
            const ushort* ap = A + (row0 + srow) * (size_t)K + k0 + sh;
            uint4 v0 = *reinterpret_cast<const uint4*>(ap);
            uint4 v1 = *reinterpret_cast<const uint4*>(ap + 8);
            *reinterpret_cast<uint4*>(&As[srow][sh])     = v0;
            *reinterpret_cast<uint4*>(&As[srow][sh + 8]) = v1;
            const ushort* bp = Bt + (size_t)(col0 + srow) * K + k0 + sh;
            uint4 w0 = *reinterpret_cast<const uint4*>(bp);
            uint4 w1 = *reinterpret_cast<const uint4*>(bp + 8);
            *reinterpret_cast<uint4*>(&Bs[srow][sh])     = w0;
            *reinterpret_cast<uint4*>(&Bs[srow][sh + 8]) = w1;
        }
        __syncthreads();
        const int l15 = lane & 15, lk = (lane >> 4) << 3;
        short8v af[4], bf[4];
        #pragma unroll
        for (int f = 0; f < 4; ++f) {
            af[f] = *reinterpret_cast<const short8v*>(&As[(wr << 6) + (f << 4) + l15][lk]);
            bf[f] = *reinterpret_cast<const short8v*>(&Bs[(wc << 6) + (f << 4) + l15][lk]);
        }
        #pragma unroll
        for (int i = 0; i < 4; ++i)
            #pragma unroll
            for (int j = 0; j < 4; ++j)
                acc[i][j] = __builtin_amdgcn_mfma_f32_16x16x32_bf16(af[i], bf[j], acc[i][j], 0, 0, 0);
        __syncthreads();
    }

    const int l15 = lane & 15, lr4 = (lane >> 4) << 2;
    #pragma unroll
    for (int i = 0; i < 4; ++i) {
        #pragma unroll
        for (int j = 0; j < 4; ++j) {
            int col = col0 + (wc << 6) + (j << 4) + l15;
            float bv = bias[col];
            #pragma unroll
            for (int rj = 0; rj < 4; ++rj) {
                size_t row = row0 + (wr << 6) + (i << 4) + lr4 + rj;
                float v = acc[i][j][rj] + bv;
                if (RELU) v = fmaxf(v, 0.f);
                if (OUTBF16)
                    reinterpret_cast<ushort*>(Cout)[row * Nout + col] = f2bf(v);
                else
                    reinterpret_cast<float*>(Cout)[row * Nout + col] = v;
            }
        }
    }
}

// ---------------- final commit reduction (512 partials) ---------------------------
__global__ __launch_bounds__(256)
void commit_finalize(const double* __restrict__ commitPart, float* __restrict__ outCommit)
{
    __shared__ double sred[256];
    const int t = threadIdx.x;
    double s = 0.0;
    for (int i = t; i < NPART; i += 256) s += commitPart[i];
    sred[t] = s;
    __syncthreads();
    for (int st = 128; st > 0; st >>= 1) {
        if (t < st) sred[t] += sred[t + st];
        __syncthreads();
    }
    if (t == 0)
        outCommit[0] = (float)(sred[0] / ((double)N_ROWS * (double)L_DIM));
}

extern "C" void kernel_launch(void* const* d_in, const int* in_sizes, int n_in,
                              void* d_out, int out_size, void* d_ws, size_t ws_size,
                              hipStream_t stream)
{
    const float* x      = (const float*)d_in[0];
    const float* enc_w1 = (const float*)d_in[1];
    const float* enc_b1 = (const float*)d_in[2];
    const float* enc_w2 = (const float*)d_in[3];
    const float* enc_b2 = (const float*)d_in[4];
    const float* enc_w3 = (const float*)d_in[5];
    const float* enc_b3 = (const float*)d_in[6];
    const float* dec_w1 = (const float*)d_in[7];
    const float* dec_b1 = (const float*)d_in[8];
    const float* dec_w2 = (const float*)d_in[9];
    const float* dec_b2 = (const float*)d_in[10];
    const float* dec_w3 = (const float*)d_in[11];
    const float* dec_b3 = (const float*)d_in[12];
    const float* cbs    = (const float*)d_in[13];

    float* out       = (float*)d_out;
    float* xrec      = out;
    float* idxOut    = out + (size_t)N_ROWS * D_IN;
    float* commitOut = idxOut + (size_t)N_ROWS * Q_ST;

    // ws layout (r6):
    //   cnorm  f32[2048]   @0       | commit f64[512] @8192
    //   w1t u16[256*32]    @12288   | w2t u16[256*256] @28672 | w3t u16[384*256] @159744
    //   bufs @360448
    char*   wsb        = (char*)d_ws;
    float*  cnorm      = (float*)wsb;
    double* commitPart = (double*)(wsb + 8192);
    ushort* w1t        = (ushort*)(wsb + 12288);
    ushort* w2t        = (ushort*)(wsb + 28672);
    ushort* w3t        = (ushort*)(wsb + 159744);
    char*   bufs       = wsb + 360448;

    // per-row bytes: zbuf 128 + bufA 1024 + bufB 1024 + zqb 64 + h1b 512 + h2b 512 = 3264
    size_t availB = (ws_size > 360448) ? ws_size - 360448 : 0;
    long long chunk = (long long)(availB / 3264);
    chunk = (chunk / 256) * 256;
    if (chunk > N_ROWS) chunk = N_ROWS;
    if (chunk < 256) chunk = 256;

    float*  zbuf = (float*)bufs;
    float*  bufA = zbuf + (size_t)chunk * L_DIM;
    float*  bufB = bufA + (size_t)chunk * H_DIM;
    ushort* zqb  = (ushort*)(bufB + (size_t)chunk * H_DIM);
    ushort* h1b  = zqb + (size_t)chunk * L_DIM;
    ushort* h2b  = h1b + (size_t)chunk * H_DIM;

    cnorm_kernel<<<8, 256, 0, stream>>>(cbs, cnorm);
    prep_wt<<<(L_DIM  * H_DIM + 255) / 256, 256, 0, stream>>>(dec_w1, w1t, L_DIM, H_DIM);
    prep_wt<<<(H_DIM * H_DIM + 255) / 256, 256, 0, stream>>>(dec_w2, w2t, H_DIM, H_DIM);
    prep_wt<<<(H_DIM * D_IN + 255) / 256, 256, 0, stream>>>(dec_w3, w3t, H_DIM, D_IN);

    for (long long ro = 0; ro < N_ROWS; ro += chunk) {
        long long R = N_ROWS - ro;
        if (R > chunk) R = chunk;
        dim3 g2((unsigned)(R / 128), 2);
        dim3 g3((unsigned)(R / 128), 3);
        // encoder (bit-exact fp32)
        gemm_bias<true><<<g2, 256, 0, stream>>>(x + ro * D_IN, enc_w1, enc_b1, bufA, D_IN, H_DIM);
        gemm_bias<true><<<g2, 256, 0, stream>>>(bufA, enc_w2, enc_b2, bufB, H_DIM, H_DIM);
        gemm_z<<<(unsigned)(R / 128), 256, 0, stream>>>(bufB, enc_w3, enc_b3, zbuf);
        // residual VQ (bit-exact; writes bf16 z_q)
        vq7_kernel<<<(unsigned)(R / VQ_RPB), 128, 0, stream>>>(zbuf, cbs, cnorm, zqb,
                                                               idxOut, commitPart, (int)ro);
        // decoder (bf16 MFMA)
        mfma_gemm<true,  true ><<<g2, 256, 0, stream>>>(zqb, w1t, dec_b1, h1b, L_DIM, H_DIM);
        mfma_gemm<true,  true ><<<g2, 256, 0, stream>>>(h1b, w2t, dec_b2, h2b, H_DIM, H_DIM);
        mfma_gemm<false, false><<<g3, 256, 0, stream>>>(h2b, w3t, dec_b3, xrec + ro * D_IN, H_DIM, D_IN);
    }

    commit_finalize<<<1, 256, 0, stream>>>(commitPart, commitOut);
}

// Round 11
// 932.356 us; speedup vs baseline: 1.7011x; 1.1454x over previous
//
#include <hip/hip_runtime.h>
#include <hip/hip_bf16.h>
#include <math.h>

// RQ-VAE pipeline. Index path = numpy-fp32 bit-exact (validated r3-r6).
// Round 11: vq9 — 2 rows/lane (halves the structurally-fixed broadcast-DS
// instruction count) + 4-wave col-split of the codebook scan (keeps 1024
// blocks -> 2 blocks/CU x 4 waves = 2 waves/SIMD latency hiding) + full 64KB
// LDS staging. Cross-wave argmin merge = lexicographic (d, idx) via LDS
// (r4-validated == np first-min); residual update replicated in all waves
// (r9-validated determinism). Inner dual-row loop = r10's (numerically OK).
// GEMMs/decoder/prep = r6-exact.

#define N_ROWS 131072
#define D_IN   384
#define H_DIM  256
#define L_DIM  32
#define K_CB   512
#define Q_ST   4
#define VQ_RPB 128                 // rows per VQ block
#define NPART  (N_ROWS / VQ_RPB)   // 1024 commit partials

typedef __attribute__((ext_vector_type(8))) short short8v;
typedef __attribute__((ext_vector_type(4))) float f32x4;

__device__ __forceinline__ ushort f2bf(float v)
{
    __hip_bfloat16 b = __float2bfloat16(v);
    return *reinterpret_cast<ushort*>(&b);
}

// np.sum(v*v) for n=32: numpy pairwise 8-accumulator order, products pre-rounded.
__device__ __forceinline__ float np_sumsq32(const float* __restrict__ v)
{
    #pragma clang fp contract(off)
    float s0 = v[0]*v[0], s1 = v[1]*v[1], s2 = v[2]*v[2], s3 = v[3]*v[3];
    float s4 = v[4]*v[4], s5 = v[5]*v[5], s6 = v[6]*v[6], s7 = v[7]*v[7];
    s0 = s0 + v[8]*v[8];   s1 = s1 + v[9]*v[9];   s2 = s2 + v[10]*v[10]; s3 = s3 + v[11]*v[11];
    s4 = s4 + v[12]*v[12]; s5 = s5 + v[13]*v[13]; s6 = s6 + v[14]*v[14]; s7 = s7 + v[15]*v[15];
    s0 = s0 + v[16]*v[16]; s1 = s1 + v[17]*v[17]; s2 = s2 + v[18]*v[18]; s3 = s3 + v[19]*v[19];
    s4 = s4 + v[20]*v[20]; s5 = s5 + v[21]*v[21]; s6 = s6 + v[22]*v[22]; s7 = s7 + v[23]*v[23];
    s0 = s0 + v[24]*v[24]; s1 = s1 + v[25]*v[25]; s2 = s2 + v[26]*v[26]; s3 = s3 + v[27]*v[27];
    s4 = s4 + v[28]*v[28]; s5 = s5 + v[29]*v[29]; s6 = s6 + v[30]*v[30]; s7 = s7 + v[31]*v[31];
    return ((s0 + s1) + (s2 + s3)) + ((s4 + s5) + (s6 + s7));
}

// ---------------- fp32 tiled GEMM (encoder; bit-exact path; r6 version) -----------
template<bool RELU>
__global__ __launch_bounds__(256)
void gemm_bias(const float* __restrict__ A, const float* __restrict__ B,
               const float* __restrict__ bias, float* __restrict__ C,
               int K, int Nout)
{
    #pragma clang fp contract(off)
    __shared__ float As2[32][132];   // [k][row]
    __shared__ float Bs[32][128];    // [k][col]
    const int t  = threadIdx.x;
    const int tc = t & 15;
    const int tr = t >> 4;
    const size_t row0 = (size_t)blockIdx.x * 128;
    const int    col0 = blockIdx.y * 128;

    float acc[8][8];
    #pragma unroll
    for (int i = 0; i < 8; ++i)
        #pragma unroll
        for (int j = 0; j < 8; ++j) acc[i][j] = 0.f;

    const int ar = t >> 3, ak = (t & 7) << 2;
    const int br = t >> 5, bc = (t & 31) << 2;

    for (int k0 = 0; k0 < K; k0 += 32) {
        #pragma unroll
        for (int i = 0; i < 4; ++i) {
            int r = ar + (i << 5);
            float4 v = *reinterpret_cast<const float4*>(A + (row0 + r) * (size_t)K + k0 + ak);
            As2[ak + 0][r] = v.x; As2[ak + 1][r] = v.y;
            As2[ak + 2][r] = v.z; As2[ak + 3][r] = v.w;
        }
        #pragma unroll
        for (int i = 0; i < 4; ++i) {
            int r = br + (i << 3);
            float4 v = *reinterpret_cast<const float4*>(B + (size_t)(k0 + r) * Nout + col0 + bc);
            *reinterpret_cast<float4*>(&Bs[r][bc]) = v;
        }
        __syncthreads();
        #pragma unroll
        for (int k = 0; k < 32; ++k) {
            float a[8], b[8];
            *reinterpret_cast<float4*>(&a[0]) = *reinterpret_cast<const float4*>(&As2[k][tr << 3]);
            *reinterpret_cast<float4*>(&a[4]) = *reinterpret_cast<const float4*>(&As2[k][(tr << 3) + 4]);
            *reinterpret_cast<float4*>(&b[0]) = *reinterpret_cast<const float4*>(&Bs[k][tc << 2]);
            *reinterpret_cast<float4*>(&b[4]) = *reinterpret_cast<const float4*>(&Bs[k][(tc << 2) + 64]);
            #pragma unroll
            for (int i = 0; i < 8; ++i)
                #pragma unroll
                for (int j = 0; j < 8; ++j) acc[i][j] = fmaf(a[i], b[j], acc[i][j]);
        }
        __syncthreads();
    }

    #pragma unroll
    for (int i = 0; i < 8; ++i) {
        size_t r = row0 + (tr << 3) + i;
        int c1 = col0 + (tc << 2);
        int c2 = c1 + 64;
        float v1[4], v2[4];
        #pragma unroll
        for (int j = 0; j < 4; ++j) {
            float u1 = acc[i][j]     + bias[c1 + j];
            float u2 = acc[i][j + 4] + bias[c2 + j];
            if (RELU) { u1 = fmaxf(u1, 0.0f); u2 = fmaxf(u2, 0.0f); }
            v1[j] = u1; v2[j] = u2;
        }
        *reinterpret_cast<float4*>(C + r * Nout + c1) = *reinterpret_cast<float4*>(&v1[0]);
        *reinterpret_cast<float4*>(C + r * Nout + c2) = *reinterpret_cast<float4*>(&v2[0]);
    }
}

// ---------------- z-GEMM: Z[M,32] = A[M,256] @ W[256,32] + b (bit-exact) ----------
__global__ __launch_bounds__(256)
void gemm_z(const float* __restrict__ A, const float* __restrict__ W,
            const float* __restrict__ bv, float* __restrict__ Z)
{
    #pragma clang fp contract(off)
    __shared__ float As2[32][132];
    __shared__ float Ws[32][36];
    const int t = threadIdx.x;
    const int cgz = t & 7, rgz = t >> 3;
    const size_t row0 = (size_t)blockIdx.x * 128;

    float acc[4][4];
    #pragma unroll
    for (int i = 0; i < 4; ++i)
        #pragma unroll
        for (int j = 0; j < 4; ++j) acc[i][j] = 0.f;

    const int ar = t >> 3, ak = (t & 7) << 2;
    for (int k0 = 0; k0 < H_DIM; k0 += 32) {
        #pragma unroll
        for (int i = 0; i < 4; ++i) {
            int r = ar + (i << 5);
            float4 v = *reinterpret_cast<const float4*>(A + (row0 + r) * (size_t)H_DIM + k0 + ak);
            As2[ak + 0][r] = v.x; As2[ak + 1][r] = v.y;
            As2[ak + 2][r] = v.z; As2[ak + 3][r] = v.w;
        }
        {
            int kr = t >> 3, cc = (t & 7) << 2;
            float4 v = *reinterpret_cast<const float4*>(W + (size_t)(k0 + kr) * L_DIM + cc);
            *reinterpret_cast<float4*>(&Ws[kr][cc]) = v;
        }
        __syncthreads();
        #pragma unroll
        for (int k = 0; k < 32; ++k) {
            float a[4], w[4];
            *reinterpret_cast<float4*>(&a[0]) = *reinterpret_cast<const float4*>(&As2[k][rgz << 2]);
            *reinterpret_cast<float4*>(&w[0]) = *reinterpret_cast<const float4*>(&Ws[k][cgz << 2]);
            #pragma unroll
            for (int i = 0; i < 4; ++i)
                #pragma unroll
                for (int j = 0; j < 4; ++j) acc[i][j] = fmaf(a[i], w[j], acc[i][j]);
        }
        __syncthreads();
    }
    #pragma unroll
    for (int i = 0; i < 4; ++i) {
        size_t row = row0 + (rgz << 2) + i;
        float v[4];
        #pragma unroll
        for (int j = 0; j < 4; ++j) v[j] = acc[i][j] + bv[(cgz << 2) + j];
        *reinterpret_cast<float4*>(Z + row * L_DIM + (cgz << 2)) = *reinterpret_cast<float4*>(&v[0]);
    }
}

// ---------------- cnorm (numpy order) ---------------------------------------------
__global__ __launch_bounds__(256)
void cnorm_kernel(const float* __restrict__ cbs, float* __restrict__ cnorm)
{
    #pragma clang fp contract(off)
    int g = blockIdx.x * 256 + threadIdx.x;
    const float* c = cbs + (size_t)g * L_DIM;
    float cl[L_DIM];
    #pragma unroll
    for (int l = 0; l < L_DIM; ++l) cl[l] = c[l];
    cnorm[g] = np_sumsq32(cl);
}

// ---------------- dec-weight prep: fp32 [K][N] -> bf16 transposed [N][K] ----------
__global__ __launch_bounds__(256)
void prep_wt(const float* __restrict__ W, ushort* __restrict__ Wt, int K, int N)
{
    int g = blockIdx.x * 256 + threadIdx.x;
    if (g >= K * N) return;
    int n = g / K, k = g - n * K;
    Wt[g] = f2bf(W[(size_t)k * N + n]);
}

// ---------------- residual VQ v9: dual-row + 4-wave col-split ---------------------
// Block: 256 thr = 4 waves; 128 rows (lane l owns rows l and l+64, same rows in
// every wave). Full 64KB codebook + cnorm staged in LDS. Wave w scans cols
// [128w, 128w+128) with broadcast ds_reads shared by both rows (halves DS
// instrs/row vs vq3). Cross-wave merge: lexicographic (d, idx) via LDS ==
// np first-min for any col distribution. All waves replicate the residual
// update with identical fp ops (deterministic). 1024 blocks -> 2/CU resident.
__global__ __launch_bounds__(256)
void vq9_kernel(const float* __restrict__ zbuf, const float* __restrict__ cbs,
                const float* __restrict__ cnorm_g, ushort* __restrict__ zqb,
                float* __restrict__ idxOut, double* __restrict__ commitPart,
                int rowBase)
{
    #pragma clang fp contract(off)
    __shared__ float  cbL[K_CB * L_DIM];   // 64 KB
    __shared__ float  cnL[K_CB];           // 2 KB
    __shared__ float  sd0[4][64], sd1[4][64];   // per-wave best d
    __shared__ int    si0[4][64], si1[4][64];   // per-wave best idx
    __shared__ double sred[256];           // 2 KB

    const int t = threadIdx.x;
    const int w = t >> 6;        // wave id = col quarter
    const int l = t & 63;        // lane = base row
    const size_t lrow0 = (size_t)blockIdx.x * VQ_RPB + l;   // row A
    const size_t lrow1 = lrow0 + 64;                        // row B
    const size_t grow0 = (size_t)rowBase + lrow0;
    const size_t grow1 = (size_t)rowBase + lrow1;
    const int c0 = w << 7;       // this wave's col base

    float r0[L_DIM], r1[L_DIM];
    {
        const float4* zp0 = reinterpret_cast<const float4*>(zbuf + lrow0 * L_DIM);
        const float4* zp1 = reinterpret_cast<const float4*>(zbuf + lrow1 * L_DIM);
        #pragma unroll
        for (int j = 0; j < 8; ++j) {
            float4 a = zp0[j], b = zp1[j];
            r0[4*j+0]=a.x; r0[4*j+1]=a.y; r0[4*j+2]=a.z; r0[4*j+3]=a.w;
            r1[4*j+0]=b.x; r1[4*j+1]=b.y; r1[4*j+2]=b.z; r1[4*j+3]=b.w;
        }
    }

    int bidx0[Q_ST], bidx1[Q_ST];
    double cAcc = 0.0;

    #pragma unroll 1
    for (int q = 0; q < Q_ST; ++q) {
        __syncthreads();   // prior stage's cbL/sd/si reads done before overwrite
        {
            const float4* src = reinterpret_cast<const float4*>(cbs + (size_t)q * K_CB * L_DIM);
            float4* dst = reinterpret_cast<float4*>(cbL);
            #pragma unroll
            for (int i = 0; i < 16; ++i) dst[t + (i << 8)] = src[t + (i << 8)];
            cnL[t]       = cnorm_g[q * K_CB + t];
            cnL[t + 256] = cnorm_g[q * K_CB + t + 256];
        }
        __syncthreads();

        float rr0 = np_sumsq32(r0);
        float rr1 = np_sumsq32(r1);
        float bd0 = __builtin_inff(), bd1 = __builtin_inff();
        int   bi0 = c0, bi1 = c0;

        // scan this wave's col quarter, dual-row shared broadcast reads
        #pragma unroll 1
        for (int cc = 0; cc < 128; cc += 2) {
            const int c = c0 + cc;
            const float4* w0 = reinterpret_cast<const float4*>(cbL + (c << 5));
            const float4* w1 = w0 + 8;
            float a00 = 0.f, a01 = 0.f, a10 = 0.f, a11 = 0.f;
            #pragma unroll
            for (int j = 0; j < 8; ++j) {
                float4 u = w0[j], v = w1[j];   // broadcast, shared by both rows
                a00 = fmaf(r0[4*j+0], u.x, a00);  a01 = fmaf(r0[4*j+0], v.x, a01);
                a10 = fmaf(r1[4*j+0], u.x, a10);  a11 = fmaf(r1[4*j+0], v.x, a11);
                a00 = fmaf(r0[4*j+1], u.y, a00);  a01 = fmaf(r0[4*j+1], v.y, a01);
                a10 = fmaf(r1[4*j+1], u.y, a10);  a11 = fmaf(r1[4*j+1], v.y, a11);
                a00 = fmaf(r0[4*j+2], u.z, a00);  a01 = fmaf(r0[4*j+2], v.z, a01);
                a10 = fmaf(r1[4*j+2], u.z, a10);  a11 = fmaf(r1[4*j+2], v.z, a11);
                a00 = fmaf(r0[4*j+3], u.w, a00);  a01 = fmaf(r0[4*j+3], v.w, a01);
                a10 = fmaf(r1[4*j+3], u.w, a10);  a11 = fmaf(r1[4*j+3], v.w, a11);
            }
            float cn0 = cnL[c], cn1 = cnL[c + 1];
            float d00 = (rr0 - 2.0f * a00) + cn0;
            float d01 = (rr0 - 2.0f * a01) + cn1;
            float d10 = (rr1 - 2.0f * a10) + cn0;
            float d11 = (rr1 - 2.0f * a11) + cn1;
            if (d00 < bd0) { bd0 = d00; bi0 = c; }       // strict < ascending
            if (d01 < bd0) { bd0 = d01; bi0 = c + 1; }
            if (d10 < bd1) { bd1 = d10; bi1 = c; }
            if (d11 < bd1) { bd1 = d11; bi1 = c + 1; }
        }

        sd0[w][l] = bd0; si0[w][l] = bi0;
        sd1[w][l] = bd1; si1[w][l] = bi1;
        __syncthreads();

        // 4-way lexicographic merge (every wave computes identical winners)
        float g0 = sd0[0][l]; int gi0 = si0[0][l];
        float g1 = sd1[0][l]; int gi1 = si1[0][l];
        #pragma unroll
        for (int ww = 1; ww < 4; ++ww) {
            float od = sd0[ww][l]; int oi = si0[ww][l];
            if (od < g0 || (od == g0 && oi < gi0)) { g0 = od; gi0 = oi; }
            od = sd1[ww][l]; oi = si1[ww][l];
            if (od < g1 || (od == g1 && oi < gi1)) { g1 = od; gi1 = oi; }
        }
        bidx0[q] = gi0;
        bidx1[q] = gi1;

        // winner gathers from LDS; residual + commit, np op order, replicated
        // identically in all 4 waves (same inputs -> same bits)
        {
            const float4* p0 = reinterpret_cast<const float4*>(cbL + (gi0 << 5));
            const float4* p1 = reinterpret_cast<const float4*>(cbL + (gi1 << 5));
            float cs0 = 0.f, cs1 = 0.f;
            #pragma unroll
            for (int j = 0; j < 8; ++j) {
                float4 v0 = p0[j], v1 = p1[j];
                float df;
                df = v0.x - r0[4*j+0]; cs0 = fmaf(df, df, cs0); r0[4*j+0] = r0[4*j+0] - v0.x;
                df = v0.y - r0[4*j+1]; cs0 = fmaf(df, df, cs0); r0[4*j+1] = r0[4*j+1] - v0.y;
                df = v0.z - r0[4*j+2]; cs0 = fmaf(df, df, cs0); r0[4*j+2] = r0[4*j+2] - v0.z;
                df = v0.w - r0[4*j+3]; cs0 = fmaf(df, df, cs0); r0[4*j+3] = r0[4*j+3] - v0.w;
                df = v1.x - r1[4*j+0]; cs1 = fmaf(df, df, cs1); r1[4*j+0] = r1[4*j+0] - v1.x;
                df = v1.y - r1[4*j+1]; cs1 = fmaf(df, df, cs1); r1[4*j+1] = r1[4*j+1] - v1.y;
                df = v1.z - r1[4*j+2]; cs1 = fmaf(df, df, cs1); r1[4*j+2] = r1[4*j+2] - v1.z;
                df = v1.w - r1[4*j+3]; cs1 = fmaf(df, df, cs1); r1[4*j+3] = r1[4*j+3] - v1.w;
            }
            if (w == 0) { cAcc += (double)cs0; cAcc += (double)cs1; }
        }
    }

    if (w == 0) {
        float4 iv0 = make_float4((float)bidx0[0], (float)bidx0[1], (float)bidx0[2], (float)bidx0[3]);
        float4 iv1 = make_float4((float)bidx1[0], (float)bidx1[1], (float)bidx1[2], (float)bidx1[3]);
        *reinterpret_cast<float4*>(idxOut + grow0 * Q_ST) = iv0;
        *reinterpret_cast<float4*>(idxOut + grow1 * Q_ST) = iv1;

        // z_q = z - r_final (re-read z), stored bf16 for the MFMA decoder
        const float4* zp0 = reinterpret_cast<const float4*>(zbuf + lrow0 * L_DIM);
        const float4* zp1 = reinterpret_cast<const float4*>(zbuf + lrow1 * L_DIM);
        ushort zq0[L_DIM], zq1[L_DIM];
        #pragma unroll
        for (int j = 0; j < 8; ++j) {
            float4 a = zp0[j], b = zp1[j];
            zq0[4*j+0] = f2bf(a.x - r0[4*j+0]);
            zq0[4*j+1] = f2bf(a.y - r0[4*j+1]);
            zq0[4*j+2] = f2bf(a.z - r0[4*j+2]);
            zq0[4*j+3] = f2bf(a.w - r0[4*j+3]);
            zq1[4*j+0] = f2bf(b.x - r1[4*j+0]);
            zq1[4*j+1] = f2bf(b.y - r1[4*j+1]);
            zq1[4*j+2] = f2bf(b.z - r1[4*j+2]);
            zq1[4*j+3] = f2bf(b.w - r1[4*j+3]);
        }
        uint4* o0 = reinterpret_cast<uint4*>(zqb + lrow0 * L_DIM);
        uint4* o1 = reinterpret_cast<uint4*>(zqb + lrow1 * L_DIM);
        const uint4* s0 = reinterpret_cast<const uint4*>(zq0);
        const uint4* s1 = reinterpret_cast<const uint4*>(zq1);
        #pragma unroll
        for (int j = 0; j < 4; ++j) { o0[j] = s0[j]; o1[j] = s1[j]; }
    }

    sred[t] = (w == 0) ? cAcc : 0.0;
    __syncthreads();
    for (int s = 128; s > 0; s >>= 1) {
        if (t < s) sred[t] += sred[t + s];
        __syncthreads();
    }
    if (t == 0) commitPart[rowBase / VQ_RPB + blockIdx.x] = sred[0];
}

// ---------------- bf16 MFMA GEMM (decoder; r6 version) ----------------------------
template<bool RELU, bool OUTBF16>
__global__ __launch_bounds__(256)
void mfma_gemm(const ushort* __restrict__ A, const ushort* __restrict__ Bt,
               const float* __restrict__ bias, void* __restrict__ Cout,
               int K, int Nout)
{
    __shared__ ushort As[128][40];
    __shared__ ushort Bs[128][40];
    const int t    = threadIdx.x;
    const int lane = t & 63;
    const int wid  = t >> 6;
    const int wr = wid >> 1, wc = wid & 1;
    const size_t row0 = (size_t)blockIdx.x * 128;
    const int    col0 = blockIdx.y * 128;

    f32x4 acc[4][4] = {};
    const int srow = t >> 1;
    const int sh   = (t & 1) << 4;

    for (int k0 = 0; k0 < K; k0 += 32) {
        {
            const ushort* ap = A + (row0 + srow) * (size_t)K + k0 + sh;
            uint4 v0 = *reinterpret_cast<const uint4*>(ap);
            uint4 v1 = *reinterpret_cast<const uint4*>(ap + 8);
            *reinterpret_cast<uint4*>(&As[srow][sh])     = v0;
            *reinterpret_cast<uint4*>(&As[srow][sh + 8]) = v1;
            const ushort* bp = Bt + (size_t)(col0 + srow) * K + k0 + sh;
            uint4 w0 = *reinterpret_cast<const uint4*>(bp);
            uint4 w1 = *reinterpret_cast<const uint4*>(bp + 8);
            *reinterpret_cast<uint4*>(&Bs[srow][sh])     = w0;
            *reinterpret_cast<uint4*>(&Bs[srow][sh + 8]) = w1;
        }
        __syncthreads();
        const int l15 = lane & 15, lk = (lane >> 4) << 3;
        short8v af[4], bf[4];
        #pragma unroll
        for (int f = 0; f < 4; ++f) {
            af[f] = *reinterpret_cast<const short8v*>(&As[(wr << 6) + (f << 4) + l15][lk]);
            bf[f] = *reinterpret_cast<const short8v*>(&Bs[(wc << 6) + (f << 4) + l15][lk]);
        }
        #pragma unroll
        for (int i = 0; i < 4; ++i)
            #pragma unroll
            for (int j = 0; j < 4; ++j)
                acc[i][j] = __builtin_amdgcn_mfma_f32_16x16x32_bf16(af[i], bf[j], acc[i][j], 0, 0, 0);
        __syncthreads();
    }

    const int l15 = lane & 15, lr4 = (lane >> 4) << 2;
    #pragma unroll
    for (int i = 0; i < 4; ++i) {
        #pragma unroll
        for (int j = 0; j < 4; ++j) {
            int col = col0 + (wc << 6) + (j << 4) + l15;
            float bv = bias[col];
            #pragma unroll
            for (int rj = 0; rj < 4; ++rj) {
                size_t row = row0 + (wr << 6) + (i << 4) + lr4 + rj;
                float v = acc[i][j][rj] + bv;
                if (RELU) v = fmaxf(v, 0.f);
                if (OUTBF16)
                    reinterpret_cast<ushort*>(Cout)[row * Nout + col] = f2bf(v);
                else
                    reinterpret_cast<float*>(Cout)[row * Nout + col] = v;
            }
        }
    }
}

// ---------------- final commit reduction (1024 partials) --------------------------
__global__ __launch_bounds__(256)
void commit_finalize(const double* __restrict__ commitPart, float* __restrict__ outCommit)
{
    __shared__ double sred[256];
    const int t = threadIdx.x;
    double s = 0.0;
    for (int i = t; i < NPART; i += 256) s += commitPart[i];
    sred[t] = s;
    __syncthreads();
    for (int st = 128; st > 0; st >>= 1) {
        if (t < st) sred[t] += sred[t + st];
        __syncthreads();
    }
    if (t == 0)
        outCommit[0] = (float)(sred[0] / ((double)N_ROWS * (double)L_DIM));
}

extern "C" void kernel_launch(void* const* d_in, const int* in_sizes, int n_in,
                              void* d_out, int out_size, void* d_ws, size_t ws_size,
                              hipStream_t stream)
{
    const float* x      = (const float*)d_in[0];
    const float* enc_w1 = (const float*)d_in[1];
    const float* enc_b1 = (const float*)d_in[2];
    const float* enc_w2 = (const float*)d_in[3];
    const float* enc_b2 = (const float*)d_in[4];
    const float* enc_w3 = (const float*)d_in[5];
    const float* enc_b3 = (const float*)d_in[6];
    const float* dec_w1 = (const float*)d_in[7];
    const float* dec_b1 = (const float*)d_in[8];
    const float* dec_w2 = (const float*)d_in[9];
    const float* dec_b2 = (const float*)d_in[10];
    const float* dec_w3 = (const float*)d_in[11];
    const float* dec_b3 = (const float*)d_in[12];
    const float* cbs    = (const float*)d_in[13];

    float* out       = (float*)d_out;
    float* xrec      = out;
    float* idxOut    = out + (size_t)N_ROWS * D_IN;
    float* commitOut = idxOut + (size_t)N_ROWS * Q_ST;

    // ws layout:
    //   cnorm  f32[2048]     @0      (8192)
    //   commit f64[1024]     @8192   (8192)
    //   w1t    u16[256*32]   @16384  (16384)
    //   w2t    u16[256*256]  @32768  (131072)
    //   w3t    u16[384*256]  @163840 (196608)
    //   bufs                 @360448
    char*   wsb        = (char*)d_ws;
    float*  cnorm      = (float*)wsb;
    double* commitPart = (double*)(wsb + 8192);
    ushort* w1t        = (ushort*)(wsb + 16384);
    ushort* w2t        = (ushort*)(wsb + 32768);
    ushort* w3t        = (ushort*)(wsb + 163840);
    char*   bufs       = wsb + 360448;

    // per-row bytes: zbuf 128 + bufA 1024 + bufB 1024 + zqb 64 + h1b 512 + h2b 512 = 3264
    size_t availB = (ws_size > 360448) ? ws_size - 360448 : 0;
    long long chunk = (long long)(availB / 3264);
    chunk = (chunk / 256) * 256;
    if (chunk > N_ROWS) chunk = N_ROWS;
    if (chunk < 256) chunk = 256;

    float*  zbuf = (float*)bufs;
    float*  bufA = zbuf + (size_t)chunk * L_DIM;
    float*  bufB = bufA + (size_t)chunk * H_DIM;
    ushort* zqb  = (ushort*)(bufB + (size_t)chunk * H_DIM);
    ushort* h1b  = zqb + (size_t)chunk * L_DIM;
    ushort* h2b  = h1b + (size_t)chunk * H_DIM;

    cnorm_kernel<<<8, 256, 0, stream>>>(cbs, cnorm);
    prep_wt<<<(L_DIM  * H_DIM + 255) / 256, 256, 0, stream>>>(dec_w1, w1t, L_DIM, H_DIM);
    prep_wt<<<(H_DIM * H_DIM + 255) / 256, 256, 0, stream>>>(dec_w2, w2t, H_DIM, H_DIM);
    prep_wt<<<(H_DIM * D_IN + 255) / 256, 256, 0, stream>>>(dec_w3, w3t, H_DIM, D_IN);

    for (long long ro = 0; ro < N_ROWS; ro += chunk) {
        long long R = N_ROWS - ro;
        if (R > chunk) R = chunk;
        dim3 g2((unsigned)(R / 128), 2);
        dim3 g3((unsigned)(R / 128), 3);
        // encoder (bit-exact fp32)
        gemm_bias<true><<<g2, 256, 0, stream>>>(x + ro * D_IN, enc_w1, enc_b1, bufA, D_IN, H_DIM);
        gemm_bias<true><<<g2, 256, 0, stream>>>(bufA, enc_w2, enc_b2, bufB, H_DIM, H_DIM);
        gemm_z<<<(unsigned)(R / 128), 256, 0, stream>>>(bufB, enc_w3, enc_b3, zbuf);
        // residual VQ (bit-exact; writes bf16 z_q)
        vq9_kernel<<<(unsigned)(R / VQ_RPB), 256, 0, stream>>>(zbuf, cbs, cnorm, zqb,
                                                               idxOut, commitPart, (int)ro);
        // decoder (bf16 MFMA)
        mfma_gemm<true,  true ><<<g2, 256, 0, stream>>>(zqb, w1t, dec_b1, h1b, L_DIM, H_DIM);
        mfma_gemm<true,  true ><<<g2, 256, 0, stream>>>(h1b, w2t, dec_b2, h2b, H_DIM, H_DIM);
        mfma_gemm<false, false><<<g3, 256, 0, stream>>>(h2b, w3t, dec_b3, xrec + ro * D_IN, H_DIM, D_IN);
    }

    commit_finalize<<<1, 256, 0, stream>>>(commitPart, commitOut);
}

// Round 12
// 919.324 us; speedup vs baseline: 1.7252x; 1.0142x over previous
//
#include <hip/hip_runtime.h>
#include <hip/hip_bf16.h>
#include <math.h>

// RQ-VAE pipeline. Index path = numpy-fp32 bit-exact (validated r3-r11).
// Round 12: encoder fp32 GEMM gets a 128x256 tile (8x16/thread, 21:1 FMA:LDS
// ratio, 128-FMA bursts hide LDS latency) + conflict-free A-staging (pad 133).
// Per-element chains (sequential-K single-acc fmaf) untouched -> bit-exact.
// vq9 / gemm_z / MFMA decoder / prep = r11.

#define N_ROWS 131072
#define D_IN   384
#define H_DIM  256
#define L_DIM  32
#define K_CB   512
#define Q_ST   4
#define VQ_RPB 128                 // rows per VQ block
#define NPART  (N_ROWS / VQ_RPB)   // 1024 commit partials

typedef __attribute__((ext_vector_type(8))) short short8v;
typedef __attribute__((ext_vector_type(4))) float f32x4;

__device__ __forceinline__ ushort f2bf(float v)
{
    __hip_bfloat16 b = __float2bfloat16(v);
    return *reinterpret_cast<ushort*>(&b);
}

// np.sum(v*v) for n=32: numpy pairwise 8-accumulator order, products pre-rounded.
__device__ __forceinline__ float np_sumsq32(const float* __restrict__ v)
{
    #pragma clang fp contract(off)
    float s0 = v[0]*v[0], s1 = v[1]*v[1], s2 = v[2]*v[2], s3 = v[3]*v[3];
    float s4 = v[4]*v[4], s5 = v[5]*v[5], s6 = v[6]*v[6], s7 = v[7]*v[7];
    s0 = s0 + v[8]*v[8];   s1 = s1 + v[9]*v[9];   s2 = s2 + v[10]*v[10]; s3 = s3 + v[11]*v[11];
    s4 = s4 + v[12]*v[12]; s5 = s5 + v[13]*v[13]; s6 = s6 + v[14]*v[14]; s7 = s7 + v[15]*v[15];
    s0 = s0 + v[16]*v[16]; s1 = s1 + v[17]*v[17]; s2 = s2 + v[18]*v[18]; s3 = s3 + v[19]*v[19];
    s4 = s4 + v[20]*v[20]; s5 = s5 + v[21]*v[21]; s6 = s6 + v[22]*v[22]; s7 = s7 + v[23]*v[23];
    s0 = s0 + v[24]*v[24]; s1 = s1 + v[25]*v[25]; s2 = s2 + v[26]*v[26]; s3 = s3 + v[27]*v[27];
    s4 = s4 + v[28]*v[28]; s5 = s5 + v[29]*v[29]; s6 = s6 + v[30]*v[30]; s7 = s7 + v[31]*v[31];
    return ((s0 + s1) + (s2 + s3)) + ((s4 + s5) + (s6 + s7));
}

// ---------------- fp32 tiled GEMM (encoder; bit-exact path) -----------------------
// 128 rows x 256 cols per block (Nout==256 for enc1/enc2), BK=32, 256 threads,
// 8 rows x 16 cols per thread. Per k: 2 a-b128 + 4 b-b128 reads vs 128 FMAs.
// As2 padded to 133 (ak-phase staging writes hit 8 distinct banks). Sequential-K
// single-acc fmaf == numpy sgemm (K<=384 single KC panel).
template<bool RELU>
__global__ __launch_bounds__(256, 2)
void gemm_bias(const float* __restrict__ A, const float* __restrict__ B,
               const float* __restrict__ bias, float* __restrict__ C,
               int K)
{
    #pragma clang fp contract(off)
    __shared__ float As2[32][133];   // [k][row], pad 133 -> conflict-free writes
    __shared__ float Bs[32][256];    // [k][col]
    const int t  = threadIdx.x;
    const int tc = t & 15;
    const int tr = t >> 4;
    const size_t row0 = (size_t)blockIdx.x * 128;

    float acc[8][16];
    #pragma unroll
    for (int i = 0; i < 8; ++i)
        #pragma unroll
        for (int j = 0; j < 16; ++j) acc[i][j] = 0.f;

    const int ar = t >> 3, ak = (t & 7) << 2;   // A staging: 4 float4 / thread
    const int brow = t >> 6, bcol = (t & 63) << 2;

    for (int k0 = 0; k0 < K; k0 += 32) {
        #pragma unroll
        for (int i = 0; i < 4; ++i) {
            int r = ar + (i << 5);
            float4 v = *reinterpret_cast<const float4*>(A + (row0 + r) * (size_t)K + k0 + ak);
            As2[ak + 0][r] = v.x; As2[ak + 1][r] = v.y;
            As2[ak + 2][r] = v.z; As2[ak + 3][r] = v.w;
        }
        #pragma unroll
        for (int i = 0; i < 8; ++i) {
            int rb = brow + (i << 2);
            float4 v = *reinterpret_cast<const float4*>(B + (size_t)(k0 + rb) * H_DIM + bcol);
            *reinterpret_cast<float4*>(&Bs[rb][bcol]) = v;
        }
        __syncthreads();
        #pragma unroll
        for (int k = 0; k < 32; ++k) {
            float a[8], b[16];
            *reinterpret_cast<float4*>(&a[0]) = *reinterpret_cast<const float4*>(&As2[k][tr << 3]);
            *reinterpret_cast<float4*>(&a[4]) = *reinterpret_cast<const float4*>(&As2[k][(tr << 3) + 4]);
            #pragma unroll
            for (int g = 0; g < 4; ++g)
                *reinterpret_cast<float4*>(&b[g << 2]) =
                    *reinterpret_cast<const float4*>(&Bs[k][(g << 6) + (tc << 2)]);
            #pragma unroll
            for (int i = 0; i < 8; ++i)
                #pragma unroll
                for (int j = 0; j < 16; ++j) acc[i][j] = fmaf(a[i], b[j], acc[i][j]);
        }
        __syncthreads();
    }

    #pragma unroll
    for (int i = 0; i < 8; ++i) {
        size_t r = row0 + (tr << 3) + i;
        #pragma unroll
        for (int g = 0; g < 4; ++g) {
            int c = (g << 6) + (tc << 2);
            float v[4];
            #pragma unroll
            for (int j = 0; j < 4; ++j) {
                float u = acc[i][(g << 2) + j] + bias[c + j];
                if (RELU) u = fmaxf(u, 0.0f);
                v[j] = u;
            }
            *reinterpret_cast<float4*>(C + r * H_DIM + c) = *reinterpret_cast<float4*>(&v[0]);
        }
    }
}

// ---------------- z-GEMM: Z[M,32] = A[M,256] @ W[256,32] + b (bit-exact) ----------
__global__ __launch_bounds__(256)
void gemm_z(const float* __restrict__ A, const float* __restrict__ W,
            const float* __restrict__ bv, float* __restrict__ Z)
{
    #pragma clang fp contract(off)
    __shared__ float As2[32][133];
    __shared__ float Ws[32][36];
    const int t = threadIdx.x;
    const int cgz = t & 7, rgz = t >> 3;
    const size_t row0 = (size_t)blockIdx.x * 128;

    float acc[4][4];
    #pragma unroll
    for (int i = 0; i < 4; ++i)
        #pragma unroll
        for (int j = 0; j < 4; ++j) acc[i][j] = 0.f;

    const int ar = t >> 3, ak = (t & 7) << 2;
    for (int k0 = 0; k0 < H_DIM; k0 += 32) {
        #pragma unroll
        for (int i = 0; i < 4; ++i) {
            int r = ar + (i << 5);
            float4 v = *reinterpret_cast<const float4*>(A + (row0 + r) * (size_t)H_DIM + k0 + ak);
            As2[ak + 0][r] = v.x; As2[ak + 1][r] = v.y;
            As2[ak + 2][r] = v.z; As2[ak + 3][r] = v.w;
        }
        {
            int kr = t >> 3, cc = (t & 7) << 2;
            float4 v = *reinterpret_cast<const float4*>(W + (size_t)(k0 + kr) * L_DIM + cc);
            *reinterpret_cast<float4*>(&Ws[kr][cc]) = v;
        }
        __syncthreads();
        #pragma unroll
        for (int k = 0; k < 32; ++k) {
            float a[4], w[4];
            *reinterpret_cast<float4*>(&a[0]) = *reinterpret_cast<const float4*>(&As2[k][rgz << 2]);
            *reinterpret_cast<float4*>(&w[0]) = *reinterpret_cast<const float4*>(&Ws[k][cgz << 2]);
            #pragma unroll
            for (int i = 0; i < 4; ++i)
                #pragma unroll
                for (int j = 0; j < 4; ++j) acc[i][j] = fmaf(a[i], w[j], acc[i][j]);
        }
        __syncthreads();
    }
    #pragma unroll
    for (int i = 0; i < 4; ++i) {
        size_t row = row0 + (rgz << 2) + i;
        float v[4];
        #pragma unroll
        for (int j = 0; j < 4; ++j) v[j] = acc[i][j] + bv[(cgz << 2) + j];
        *reinterpret_cast<float4*>(Z + row * L_DIM + (cgz << 2)) = *reinterpret_cast<float4*>(&v[0]);
    }
}

// ---------------- cnorm (numpy order) ---------------------------------------------
__global__ __launch_bounds__(256)
void cnorm_kernel(const float* __restrict__ cbs, float* __restrict__ cnorm)
{
    #pragma clang fp contract(off)
    int g = blockIdx.x * 256 + threadIdx.x;
    const float* c = cbs + (size_t)g * L_DIM;
    float cl[L_DIM];
    #pragma unroll
    for (int l = 0; l < L_DIM; ++l) cl[l] = c[l];
    cnorm[g] = np_sumsq32(cl);
}

// ---------------- dec-weight prep: fp32 [K][N] -> bf16 transposed [N][K] ----------
__global__ __launch_bounds__(256)
void prep_wt(const float* __restrict__ W, ushort* __restrict__ Wt, int K, int N)
{
    int g = blockIdx.x * 256 + threadIdx.x;
    if (g >= K * N) return;
    int n = g / K, k = g - n * K;
    Wt[g] = f2bf(W[(size_t)k * N + n]);
}

// ---------------- residual VQ v9 (r11): dual-row + 4-wave col-split ---------------
__global__ __launch_bounds__(256)
void vq9_kernel(const float* __restrict__ zbuf, const float* __restrict__ cbs,
                const float* __restrict__ cnorm_g, ushort* __restrict__ zqb,
                float* __restrict__ idxOut, double* __restrict__ commitPart,
                int rowBase)
{
    #pragma clang fp contract(off)
    __shared__ float  cbL[K_CB * L_DIM];   // 64 KB
    __shared__ float  cnL[K_CB];           // 2 KB
    __shared__ float  sd0[4][64], sd1[4][64];
    __shared__ int    si0[4][64], si1[4][64];
    __shared__ double sred[256];

    const int t = threadIdx.x;
    const int w = t >> 6;
    const int l = t & 63;
    const size_t lrow0 = (size_t)blockIdx.x * VQ_RPB + l;
    const size_t lrow1 = lrow0 + 64;
    const size_t grow0 = (size_t)rowBase + lrow0;
    const size_t grow1 = (size_t)rowBase + lrow1;
    const int c0 = w << 7;

    float r0[L_DIM], r1[L_DIM];
    {
        const float4* zp0 = reinterpret_cast<const float4*>(zbuf + lrow0 * L_DIM);
        const float4* zp1 = reinterpret_cast<const float4*>(zbuf + lrow1 * L_DIM);
        #pragma unroll
        for (int j = 0; j < 8; ++j) {
            float4 a = zp0[j], b = zp1[j];
            r0[4*j+0]=a.x; r0[4*j+1]=a.y; r0[4*j+2]=a.z; r0[4*j+3]=a.w;
            r1[4*j+0]=b.x; r1[4*j+1]=b.y; r1[4*j+2]=b.z; r1[4*j+3]=b.w;
        }
    }

    int bidx0[Q_ST], bidx1[Q_ST];
    double cAcc = 0.0;

    #pragma unroll 1
    for (int q = 0; q < Q_ST; ++q) {
        __syncthreads();
        {
            const float4* src = reinterpret_cast<const float4*>(cbs + (size_t)q * K_CB * L_DIM);
            float4* dst = reinterpret_cast<float4*>(cbL);
            #pragma unroll
            for (int i = 0; i < 16; ++i) dst[t + (i << 8)] = src[t + (i << 8)];
            cnL[t]       = cnorm_g[q * K_CB + t];
            cnL[t + 256] = cnorm_g[q * K_CB + t + 256];
        }
        __syncthreads();

        float rr0 = np_sumsq32(r0);
        float rr1 = np_sumsq32(r1);
        float bd0 = __builtin_inff(), bd1 = __builtin_inff();
        int   bi0 = c0, bi1 = c0;

        #pragma unroll 1
        for (int cc = 0; cc < 128; cc += 2) {
            const int c = c0 + cc;
            const float4* w0 = reinterpret_cast<const float4*>(cbL + (c << 5));
            const float4* w1 = w0 + 8;
            float a00 = 0.f, a01 = 0.f, a10 = 0.f, a11 = 0.f;
            #pragma unroll
            for (int j = 0; j < 8; ++j) {
                float4 u = w0[j], v = w1[j];
                a00 = fmaf(r0[4*j+0], u.x, a00);  a01 = fmaf(r0[4*j+0], v.x, a01);
                a10 = fmaf(r1[4*j+0], u.x, a10);  a11 = fmaf(r1[4*j+0], v.x, a11);
                a00 = fmaf(r0[4*j+1], u.y, a00);  a01 = fmaf(r0[4*j+1], v.y, a01);
                a10 = fmaf(r1[4*j+1], u.y, a10);  a11 = fmaf(r1[4*j+1], v.y, a11);
                a00 = fmaf(r0[4*j+2], u.z, a00);  a01 = fmaf(r0[4*j+2], v.z, a01);
                a10 = fmaf(r1[4*j+2], u.z, a10);  a11 = fmaf(r1[4*j+2], v.z, a11);
                a00 = fmaf(r0[4*j+3], u.w, a00);  a01 = fmaf(r0[4*j+3], v.w, a01);
                a10 = fmaf(r1[4*j+3], u.w, a10);  a11 = fmaf(r1[4*j+3], v.w, a11);
            }
            float cn0 = cnL[c], cn1 = cnL[c + 1];
            float d00 = (rr0 - 2.0f * a00) + cn0;
            float d01 = (rr0 - 2.0f * a01) + cn1;
            float d10 = (rr1 - 2.0f * a10) + cn0;
            float d11 = (rr1 - 2.0f * a11) + cn1;
            if (d00 < bd0) { bd0 = d00; bi0 = c; }
            if (d01 < bd0) { bd0 = d01; bi0 = c + 1; }
            if (d10 < bd1) { bd1 = d10; bi1 = c; }
            if (d11 < bd1) { bd1 = d11; bi1 = c + 1; }
        }

        sd0[w][l] = bd0; si0[w][l] = bi0;
        sd1[w][l] = bd1; si1[w][l] = bi1;
        __syncthreads();

        float g0 = sd0[0][l]; int gi0 = si0[0][l];
        float g1 = sd1[0][l]; int gi1 = si1[0][l];
        #pragma unroll
        for (int ww = 1; ww < 4; ++ww) {
            float od = sd0[ww][l]; int oi = si0[ww][l];
            if (od < g0 || (od == g0 && oi < gi0)) { g0 = od; gi0 = oi; }
            od = sd1[ww][l]; oi = si1[ww][l];
            if (od < g1 || (od == g1 && oi < gi1)) { g1 = od; gi1 = oi; }
        }
        bidx0[q] = gi0;
        bidx1[q] = gi1;

        {
            const float4* p0 = reinterpret_cast<const float4*>(cbL + (gi0 << 5));
            const float4* p1 = reinterpret_cast<const float4*>(cbL + (gi1 << 5));
            float cs0 = 0.f, cs1 = 0.f;
            #pragma unroll
            for (int j = 0; j < 8; ++j) {
                float4 v0 = p0[j], v1 = p1[j];
                float df;
                df = v0.x - r0[4*j+0]; cs0 = fmaf(df, df, cs0); r0[4*j+0] = r0[4*j+0] - v0.x;
                df = v0.y - r0[4*j+1]; cs0 = fmaf(df, df, cs0); r0[4*j+1] = r0[4*j+1] - v0.y;
                df = v0.z - r0[4*j+2]; cs0 = fmaf(df, df, cs0); r0[4*j+2] = r0[4*j+2] - v0.z;
                df = v0.w - r0[4*j+3]; cs0 = fmaf(df, df, cs0); r0[4*j+3] = r0[4*j+3] - v0.w;
                df = v1.x - r1[4*j+0]; cs1 = fmaf(df, df, cs1); r1[4*j+0] = r1[4*j+0] - v1.x;
                df = v1.y - r1[4*j+1]; cs1 = fmaf(df, df, cs1); r1[4*j+1] = r1[4*j+1] - v1.y;
                df = v1.z - r1[4*j+2]; cs1 = fmaf(df, df, cs1); r1[4*j+2] = r1[4*j+2] - v1.z;
                df = v1.w - r1[4*j+3]; cs1 = fmaf(df, df, cs1); r1[4*j+3] = r1[4*j+3] - v1.w;
            }
            if (w == 0) { cAcc += (double)cs0; cAcc += (double)cs1; }
        }
    }

    if (w == 0) {
        float4 iv0 = make_float4((float)bidx0[0], (float)bidx0[1], (float)bidx0[2], (float)bidx0[3]);
        float4 iv1 = make_float4((float)bidx1[0], (float)bidx1[1], (float)bidx1[2], (float)bidx1[3]);
        *reinterpret_cast<float4*>(idxOut + grow0 * Q_ST) = iv0;
        *reinterpret_cast<float4*>(idxOut + grow1 * Q_ST) = iv1;

        const float4* zp0 = reinterpret_cast<const float4*>(zbuf + lrow0 * L_DIM);
        const float4* zp1 = reinterpret_cast<const float4*>(zbuf + lrow1 * L_DIM);
        ushort zq0[L_DIM], zq1[L_DIM];
        #pragma unroll
        for (int j = 0; j < 8; ++j) {
            float4 a = zp0[j], b = zp1[j];
            zq0[4*j+0] = f2bf(a.x - r0[4*j+0]);
            zq0[4*j+1] = f2bf(a.y - r0[4*j+1]);
            zq0[4*j+2] = f2bf(a.z - r0[4*j+2]);
            zq0[4*j+3] = f2bf(a.w - r0[4*j+3]);
            zq1[4*j+0] = f2bf(b.x - r1[4*j+0]);
            zq1[4*j+1] = f2bf(b.y - r1[4*j+1]);
            zq1[4*j+2] = f2bf(b.z - r1[4*j+2]);
            zq1[4*j+3] = f2bf(b.w - r1[4*j+3]);
        }
        uint4* o0 = reinterpret_cast<uint4*>(zqb + lrow0 * L_DIM);
        uint4* o1 = reinterpret_cast<uint4*>(zqb + lrow1 * L_DIM);
        const uint4* s0 = reinterpret_cast<const uint4*>(zq0);
        const uint4* s1 = reinterpret_cast<const uint4*>(zq1);
        #pragma unroll
        for (int j = 0; j < 4; ++j) { o0[j] = s0[j]; o1[j] = s1[j]; }
    }

    sred[t] = (w == 0) ? cAcc : 0.0;
    __syncthreads();
    for (int s = 128; s > 0; s >>= 1) {
        if (t < s) sred[t] += sred[t + s];
        __syncthreads();
    }
    if (t == 0) commitPart[rowBase / VQ_RPB + blockIdx.x] = sred[0];
}

// ---------------- bf16 MFMA GEMM (decoder; r6 version) ----------------------------
template<bool RELU, bool OUTBF16>
__global__ __launch_bounds__(256)
void mfma_gemm(const ushort* __restrict__ A, const ushort* __restrict__ Bt,
               const float* __restrict__ bias, void* __restrict__ Cout,
               int K, int Nout)
{
    __shared__ ushort As[128][40];
    __shared__ ushort Bs[128][40];
    const int t    = threadIdx.x;
    const int lane = t & 63;
    const int wid  = t >> 6;
    const int wr = wid >> 1, wc = wid & 1;
    const size_t row0 = (size_t)blockIdx.x * 128;
    const int    col0 = blockIdx.y * 128;

    f32x4 acc[4][4] = {};
    const int srow = t >> 1;
    const int sh   = (t & 1) << 4;

    for (int k0 = 0; k0 < K; k0 += 32) {
        {
            const ushort* ap = A + (row0 + srow) * (size_t)K + k0 + sh;
            uint4 v0 = *reinterpret_cast<const uint4*>(ap);
            uint4 v1 = *reinterpret_cast<const uint4*>(ap + 8);
            *reinterpret_cast<uint4*>(&As[srow][sh])     = v0;
            *reinterpret_cast<uint4*>(&As[srow][sh + 8]) = v1;
            const ushort* bp = Bt + (size_t)(col0 + srow) * K + k0 + sh;
            uint4 w0 = *reinterpret_cast<const uint4*>(bp);
            uint4 w1 = *reinterpret_cast<const uint4*>(bp + 8);
            *reinterpret_cast<uint4*>(&Bs[srow][sh])     = w0;
            *reinterpret_cast<uint4*>(&Bs[srow][sh + 8]) = w1;
        }
        __syncthreads();
        const int l15 = lane & 15, lk = (lane >> 4) << 3;
        short8v af[4], bf[4];
        #pragma unroll
        for (int f = 0; f < 4; ++f) {
            af[f] = *reinterpret_cast<const short8v*>(&As[(wr << 6) + (f << 4) + l15][lk]);
            bf[f] = *reinterpret_cast<const short8v*>(&Bs[(wc << 6) + (f << 4) + l15][lk]);
        }
        #pragma unroll
        for (int i = 0; i < 4; ++i)
            #pragma unroll
            for (int j = 0; j < 4; ++j)
                acc[i][j] = __builtin_amdgcn_mfma_f32_16x16x32_bf16(af[i], bf[j], acc[i][j], 0, 0, 0);
        __syncthreads();
    }

    const int l15 = lane & 15, lr4 = (lane >> 4) << 2;
    #pragma unroll
    for (int i = 0; i < 4; ++i) {
        #pragma unroll
        for (int j = 0; j < 4; ++j) {
            int col = col0 + (wc << 6) + (j << 4) + l15;
            float bv = bias[col];
            #pragma unroll
            for (int rj = 0; rj < 4; ++rj) {
                size_t row = row0 + (wr << 6) + (i << 4) + lr4 + rj;
                float v = acc[i][j][rj] + bv;
                if (RELU) v = fmaxf(v, 0.f);
                if (OUTBF16)
                    reinterpret_cast<ushort*>(Cout)[row * Nout + col] = f2bf(v);
                else
                    reinterpret_cast<float*>(Cout)[row * Nout + col] = v;
            }
        }
    }
}

// ---------------- final commit reduction (1024 partials) --------------------------
__global__ __launch_bounds__(256)
void commit_finalize(const double* __restrict__ commitPart, float* __restrict__ outCommit)
{
    __shared__ double sred[256];
    const int t = threadIdx.x;
    double s = 0.0;
    for (int i = t; i < NPART; i += 256) s += commitPart[i];
    sred[t] = s;
    __syncthreads();
    for (int st = 128; st > 0; st >>= 1) {
        if (t < st) sred[t] += sred[t + st];
        __syncthreads();
    }
    if (t == 0)
        outCommit[0] = (float)(sred[0] / ((double)N_ROWS * (double)L_DIM));
}

extern "C" void kernel_launch(void* const* d_in, const int* in_sizes, int n_in,
                              void* d_out, int out_size, void* d_ws, size_t ws_size,
                              hipStream_t stream)
{
    const float* x      = (const float*)d_in[0];
    const float* enc_w1 = (const float*)d_in[1];
    const float* enc_b1 = (const float*)d_in[2];
    const float* enc_w2 = (const float*)d_in[3];
    const float* enc_b2 = (const float*)d_in[4];
    const float* enc_w3 = (const float*)d_in[5];
    const float* enc_b3 = (const float*)d_in[6];
    const float* dec_w1 = (const float*)d_in[7];
    const float* dec_b1 = (const float*)d_in[8];
    const float* dec_w2 = (const float*)d_in[9];
    const float* dec_b2 = (const float*)d_in[10];
    const float* dec_w3 = (const float*)d_in[11];
    const float* dec_b3 = (const float*)d_in[12];
    const float* cbs    = (const float*)d_in[13];

    float* out       = (float*)d_out;
    float* xrec      = out;
    float* idxOut    = out + (size_t)N_ROWS * D_IN;
    float* commitOut = idxOut + (size_t)N_ROWS * Q_ST;

    // ws layout:
    //   cnorm  f32[2048]     @0      (8192)
    //   commit f64[1024]     @8192   (8192)
    //   w1t    u16[256*32]   @16384  (16384)
    //   w2t    u16[256*256]  @32768  (131072)
    //   w3t    u16[384*256]  @163840 (196608)
    //   bufs                 @360448
    char*   wsb        = (char*)d_ws;
    float*  cnorm      = (float*)wsb;
    double* commitPart = (double*)(wsb + 8192);
    ushort* w1t        = (ushort*)(wsb + 16384);
    ushort* w2t        = (ushort*)(wsb + 32768);
    ushort* w3t        = (ushort*)(wsb + 163840);
    char*   bufs       = wsb + 360448;

    // per-row bytes: zbuf 128 + bufA 1024 + bufB 1024 + zqb 64 + h1b 512 + h2b 512 = 3264
    size_t availB = (ws_size > 360448) ? ws_size - 360448 : 0;
    long long chunk = (long long)(availB / 3264);
    chunk = (chunk / 256) * 256;
    if (chunk > N_ROWS) chunk = N_ROWS;
    if (chunk < 256) chunk = 256;

    float*  zbuf = (float*)bufs;
    float*  bufA = zbuf + (size_t)chunk * L_DIM;
    float*  bufB = bufA + (size_t)chunk * H_DIM;
    ushort* zqb  = (ushort*)(bufB + (size_t)chunk * H_DIM);
    ushort* h1b  = zqb + (size_t)chunk * L_DIM;
    ushort* h2b  = h1b + (size_t)chunk * H_DIM;

    cnorm_kernel<<<8, 256, 0, stream>>>(cbs, cnorm);
    prep_wt<<<(L_DIM  * H_DIM + 255) / 256, 256, 0, stream>>>(dec_w1, w1t, L_DIM, H_DIM);
    prep_wt<<<(H_DIM * H_DIM + 255) / 256, 256, 0, stream>>>(dec_w2, w2t, H_DIM, H_DIM);
    prep_wt<<<(H_DIM * D_IN + 255) / 256, 256, 0, stream>>>(dec_w3, w3t, H_DIM, D_IN);

    for (long long ro = 0; ro < N_ROWS; ro += chunk) {
        long long R = N_ROWS - ro;
        if (R > chunk) R = chunk;
        unsigned g1 = (unsigned)(R / 128);
        dim3 g2(g1, 2);
        dim3 g3(g1, 3);
        // encoder (bit-exact fp32; 128x256 tile)
        gemm_bias<true><<<g1, 256, 0, stream>>>(x + ro * D_IN, enc_w1, enc_b1, bufA, D_IN);
        gemm_bias<true><<<g1, 256, 0, stream>>>(bufA, enc_w2, enc_b2, bufB, H_DIM);
        gemm_z<<<g1, 256, 0, stream>>>(bufB, enc_w3, enc_b3, zbuf);
        // residual VQ (bit-exact; writes bf16 z_q)
        vq9_kernel<<<(unsigned)(R / VQ_RPB), 256, 0, stream>>>(zbuf, cbs, cnorm, zqb,
                                                               idxOut, commitPart, (int)ro);
        // decoder (bf16 MFMA)
        mfma_gemm<true,  true ><<<g2, 256, 0, stream>>>(zqb, w1t, dec_b1, h1b, L_DIM, H_DIM);
        mfma_gemm<true,  true ><<<g2, 256, 0, stream>>>(h1b, w2t, dec_b2, h2b, H_DIM, H_DIM);
        mfma_gemm<false, false><<<g3, 256, 0, stream>>>(h2b, w3t, dec_b3, xrec + ro * D_IN, H_DIM, D_IN);
    }

    commit_finalize<<<1, 256, 0, stream>>>(commitPart, commitOut);
}